// Round 1
// baseline (750.021 us; speedup 1.0000x reference)
//
#include <hip/hip_runtime.h>

// ---------------------------------------------------------------------------
// SAGAN self-attention block, MI355X / gfx950.
// B=4, C=256, H=W=64 (HW=4096), Ck=32.
// Pipeline: k_sigma -> k_projkq + k_projv (fp32 vector, bf16 out) -> k_attn
// (flash attention, mfma_f32_16x16x32_bf16, hi/lo-split scores).
// ---------------------------------------------------------------------------

constexpr int kC   = 256;
constexpr int kCK  = 32;
constexpr int kHW  = 4096;
constexpr int kB   = 4;
constexpr int kCHW = kC * kHW;          // 1048576 per batch

typedef short bf16x8 __attribute__((ext_vector_type(8)));
typedef float f32x4  __attribute__((ext_vector_type(4)));

__device__ __forceinline__ unsigned short f2bf(float f) {
    union { float f; unsigned u; } v; v.f = f;
    unsigned u = v.u;
    return (unsigned short)((u + 0x7fffu + ((u >> 16) & 1u)) >> 16);  // RNE
}
__device__ __forceinline__ float bf2f(unsigned short h) {
    union { unsigned u; float f; } v; v.u = ((unsigned)h) << 16;
    return v.f;
}

// ---------------------------------------------------------------------------
// Kernel 1: inverse spectral norms.  sigma = ||W @ normalize(U @ W)||
// (with the reference's eps-clamped normalize semantics).
// block j in {0,1,2} handles f/g/h.  Writes sig[j] = 1/sigma.
// ---------------------------------------------------------------------------
__global__ __launch_bounds__(256) void k_sigma(
    const float* __restrict__ fw, const float* __restrict__ fu,
    const float* __restrict__ gw, const float* __restrict__ gu,
    const float* __restrict__ hww, const float* __restrict__ hu,
    float* __restrict__ sig)
{
    const int which = blockIdx.x;
    const float* W = which == 0 ? fw : (which == 1 ? gw : hww);
    const float* U = which == 0 ? fu : (which == 1 ? gu : hu);
    const int O = (which == 2) ? 256 : 32;
    const int t = threadIdx.x;

    __shared__ float red[256];
    __shared__ float Vv[256];

    // t1[i] = sum_o U[o] * W[o,i]   (i = t, coalesced over threads)
    float t1 = 0.f;
    for (int o = 0; o < O; ++o) t1 += U[o] * W[o * 256 + t];

    red[t] = t1 * t1;
    __syncthreads();
    for (int s = 128; s > 0; s >>= 1) { if (t < s) red[t] += red[t + s]; __syncthreads(); }
    const float n1 = sqrtf(red[0]);
    Vv[t] = t1 / fmaxf(n1, 1e-12f);
    __syncthreads();

    // t2[o] = sum_i W[o,i] * V[i]
    float t2 = 0.f;
    if (t < O) {
        for (int i = 0; i < 256; ++i) t2 += W[t * 256 + i] * Vv[i];
    }
    __syncthreads();
    red[t] = t2 * t2;
    __syncthreads();
    for (int s = 128; s > 0; s >>= 1) { if (t < s) red[t] += red[t + s]; __syncthreads(); }
    if (t == 0) {
        const float s2 = red[0];
        const float nrm = sqrtf(s2);
        const float sigma = s2 / fmaxf(nrm, 1e-12f);  // = Unew . (W V)
        sig[which] = 1.0f / sigma;
    }
}

// ---------------------------------------------------------------------------
// Kernel 2: K and Q projections.  grid (64 n-tiles, 4 b), 256 thr.
// Threads: part = tid>>6 -> {K-dlo, K-dhi, Q-dlo, Q-dhi}, 64 n per block.
// Output bf16 hi+lo pairs in [b][n][d] layout (d contiguous, 32 per row) —
// exactly the MFMA A/B fragment load order for 16x16x32.
// ---------------------------------------------------------------------------
__global__ __launch_bounds__(256) void k_projkq(
    const float* __restrict__ x,
    const float* __restrict__ fw, const float* __restrict__ fb,
    const float* __restrict__ gw, const float* __restrict__ gb,
    const float* __restrict__ sig,
    unsigned short* __restrict__ Khi, unsigned short* __restrict__ Klo,
    unsigned short* __restrict__ Qhi, unsigned short* __restrict__ Qlo)
{
    __shared__ float wT[2][256][32];   // [mat][c][d], 64 KB
    const int t = threadIdx.x;
    const int b = blockIdx.y;
    const float invf = sig[0], invg = sig[1];

    for (int idx = t; idx < 8192; idx += 256) {
        const int cc = idx >> 5, d = idx & 31;
        wT[0][cc][d] = fw[d * 256 + cc] * invf;
        wT[1][cc][d] = gw[d * 256 + cc] * invg;
    }
    __syncthreads();

    const int part = t >> 6, nl = t & 63;
    const int mat = part >> 1;
    const int dh = (part & 1) * 16;
    const int n = blockIdx.x * 64 + nl;
    const float* bias = mat ? gb : fb;

    float acc[16];
#pragma unroll
    for (int i = 0; i < 16; ++i) acc[i] = bias[dh + i];

    const float* xp = x + (size_t)b * kCHW + n;
#pragma unroll 4
    for (int cc = 0; cc < 256; ++cc) {
        const float xv = xp[(size_t)cc * kHW];
        const float* wr = &wT[mat][cc][dh];
#pragma unroll
        for (int i = 0; i < 16; ++i) acc[i] += wr[i] * xv;
    }

    unsigned ph[8], pl[8];
#pragma unroll
    for (int i = 0; i < 8; ++i) {
        const unsigned short h0 = f2bf(acc[2 * i]);
        const unsigned short h1 = f2bf(acc[2 * i + 1]);
        const unsigned short l0 = f2bf(acc[2 * i] - bf2f(h0));
        const unsigned short l1 = f2bf(acc[2 * i + 1] - bf2f(h1));
        ph[i] = (unsigned)h0 | ((unsigned)h1 << 16);
        pl[i] = (unsigned)l0 | ((unsigned)l1 << 16);
    }
    unsigned short* Hh = mat ? Qhi : Khi;
    unsigned short* Hl = mat ? Qlo : Klo;
    const size_t off = ((size_t)(b * kHW + n)) * 32 + dh;
    *(uint4*)(Hh + off)     = make_uint4(ph[0], ph[1], ph[2], ph[3]);
    *(uint4*)(Hh + off + 8) = make_uint4(ph[4], ph[5], ph[6], ph[7]);
    *(uint4*)(Hl + off)     = make_uint4(pl[0], pl[1], pl[2], pl[3]);
    *(uint4*)(Hl + off + 8) = make_uint4(pl[4], pl[5], pl[6], pl[7]);
}

// ---------------------------------------------------------------------------
// Kernel 3: V projection.  grid (16 m-tiles, 8 c-groups, 4 b), 256 thr.
// Output bf16 in [b][c][m] layout (m contiguous) — B-fragment order for PV.
// ---------------------------------------------------------------------------
__global__ __launch_bounds__(256) void k_projv(
    const float* __restrict__ x,
    const float* __restrict__ hww, const float* __restrict__ hb,
    const float* __restrict__ sig,
    unsigned short* __restrict__ Vb)
{
    __shared__ float wT[256][32];      // [c_in][c_out_local], 32 KB
    const int t = threadIdx.x;
    const int mt = blockIdx.x, cg = blockIdx.y, b = blockIdx.z;
    const float invh = sig[2];

    for (int idx = t; idx < 8192; idx += 256) {
        const int cc = idx >> 5, i = idx & 31;
        wT[cc][i] = hww[(size_t)(cg * 32 + i) * 256 + cc] * invh;
    }
    __syncthreads();

    const int m = mt * 256 + t;
    float acc[32];
#pragma unroll
    for (int i = 0; i < 32; ++i) acc[i] = hb[cg * 32 + i];

    const float* xp = x + (size_t)b * kCHW + m;
#pragma unroll 4
    for (int cc = 0; cc < 256; ++cc) {
        const float xv = xp[(size_t)cc * kHW];
#pragma unroll
        for (int i = 0; i < 32; ++i) acc[i] += wT[cc][i] * xv;
    }

    const size_t base = ((size_t)b * kC + cg * 32) * kHW + m;
#pragma unroll
    for (int i = 0; i < 32; ++i) Vb[base + (size_t)i * kHW] = f2bf(acc[i]);
}

// ---------------------------------------------------------------------------
// Kernel 4: flash attention.  grid (64 row-tiles, 4 b), 256 thr (4 waves).
// Wave handles 16 rows; m-loop over 64-wide tiles of the 4096 keys.
// Scores: 3x mfma 16x16x32 bf16 with K/Q hi-lo split (fp32-accurate scores).
// P -> A-layout via per-wave LDS round-trip (row stride 72 bf16, 16B-aligned).
// O: 16 C-frags (full 256 channels) per wave.
// ---------------------------------------------------------------------------
__global__ __launch_bounds__(256, 2) void k_attn(
    const float* __restrict__ x, const float* __restrict__ gamma,
    const unsigned short* __restrict__ Khi, const unsigned short* __restrict__ Klo,
    const unsigned short* __restrict__ Qhi, const unsigned short* __restrict__ Qlo,
    const unsigned short* __restrict__ Vb,
    float* __restrict__ out)
{
    __shared__ unsigned short Pl[4][16 * 72];   // per-wave P tile, 9 KB total

    const int t = threadIdx.x;
    const int wave = t >> 6, lane = t & 63;
    const int quad = lane >> 4, l15 = lane & 15;
    const int b = blockIdx.y;
    const int nb = blockIdx.x * 64 + wave * 16;

    // A-fragment of K for this wave's 16 rows: lane holds row l15, k = quad*8..+7
    const size_t koff = ((size_t)(b * kHW + nb + l15)) * 32 + quad * 8;
    const bf16x8 kh = *(const bf16x8*)(Khi + koff);
    const bf16x8 kl = *(const bf16x8*)(Klo + koff);

    f32x4 O[16] = {};
    float mrow[4] = { -1e30f, -1e30f, -1e30f, -1e30f };
    float lrow[4] = { 0.f, 0.f, 0.f, 0.f };

    const unsigned short* Qbh = Qhi + (size_t)b * kHW * 32;
    const unsigned short* Qbl = Qlo + (size_t)b * kHW * 32;
    const unsigned short* Vbb = Vb + (size_t)b * kC * kHW;
    unsigned short* myP = Pl[wave];

    for (int mt = 0; mt < 64; ++mt) {
        const int m0 = mt * 64;

        // ---- scores: S (16 rows x 64 cols) as 4 chunks of 16 cols ----
        f32x4 s[4];
#pragma unroll
        for (int mi = 0; mi < 4; ++mi) {
            const size_t qoff = ((size_t)(m0 + mi * 16 + l15)) * 32 + quad * 8;
            const bf16x8 qh = *(const bf16x8*)(Qbh + qoff);
            const bf16x8 ql = *(const bf16x8*)(Qbl + qoff);
            f32x4 acc = { 0.f, 0.f, 0.f, 0.f };
            acc = __builtin_amdgcn_mfma_f32_16x16x32_bf16(kl, qh, acc, 0, 0, 0);
            acc = __builtin_amdgcn_mfma_f32_16x16x32_bf16(kh, ql, acc, 0, 0, 0);
            acc = __builtin_amdgcn_mfma_f32_16x16x32_bf16(kh, qh, acc, 0, 0, 0);
            s[mi] = acc;
        }

        // ---- online softmax row stats (row = quad*4+r, cols across 16 lanes) ----
        float alpha[4];
#pragma unroll
        for (int r = 0; r < 4; ++r) {
            float v = fmaxf(fmaxf(s[0][r], s[1][r]), fmaxf(s[2][r], s[3][r]));
            v = fmaxf(v, __shfl_xor(v, 1));
            v = fmaxf(v, __shfl_xor(v, 2));
            v = fmaxf(v, __shfl_xor(v, 4));
            v = fmaxf(v, __shfl_xor(v, 8));
            const float mnew = fmaxf(mrow[r], v);
            alpha[r] = __expf(mrow[r] - mnew);
            mrow[r] = mnew;
            float rs = 0.f;
#pragma unroll
            for (int mi = 0; mi < 4; ++mi) {
                const float p = __expf(s[mi][r] - mnew);
                s[mi][r] = p;
                rs += p;
            }
            rs += __shfl_xor(rs, 1);
            rs += __shfl_xor(rs, 2);
            rs += __shfl_xor(rs, 4);
            rs += __shfl_xor(rs, 8);
            lrow[r] = lrow[r] * alpha[r] + rs;
        }

        // ---- rescale O by alpha per row ----
#pragma unroll
        for (int ct = 0; ct < 16; ++ct) {
#pragma unroll
            for (int r = 0; r < 4; ++r) O[ct][r] *= alpha[r];
        }

        // ---- P: C-layout regs -> A-layout via LDS (bf16) ----
#pragma unroll
        for (int mi = 0; mi < 4; ++mi) {
#pragma unroll
            for (int r = 0; r < 4; ++r) {
                myP[(quad * 4 + r) * 72 + mi * 16 + l15] = f2bf(s[mi][r]);
            }
        }
        __syncthreads();

        // ---- PV: O(16x256) += P(16x64) @ V^T(64x256) ----
#pragma unroll
        for (int ks = 0; ks < 2; ++ks) {
            const bf16x8 pa = *(const bf16x8*)(myP + l15 * 72 + ks * 32 + quad * 8);
#pragma unroll
            for (int ct = 0; ct < 16; ++ct) {
                const bf16x8 vb8 = *(const bf16x8*)(
                    Vbb + (size_t)(ct * 16 + l15) * kHW + m0 + ks * 32 + quad * 8);
                O[ct] = __builtin_amdgcn_mfma_f32_16x16x32_bf16(pa, vb8, O[ct], 0, 0, 0);
            }
        }
        __syncthreads();
    }

    // ---- epilogue: normalize, gamma * out + x, raw-view write ----
    const float g = gamma[0];
    float invl[4];
#pragma unroll
    for (int r = 0; r < 4; ++r) invl[r] = 1.0f / lrow[r];

#pragma unroll
    for (int ct = 0; ct < 16; ++ct) {
#pragma unroll
        for (int r = 0; r < 4; ++r) {
            const int n = nb + quad * 4 + r;
            const int c = ct * 16 + l15;
            const size_t idx = (size_t)b * kCHW + (size_t)n * 256 + c;
            out[idx] = g * (O[ct][r] * invl[r]) + x[idx];
        }
    }
}

// ---------------------------------------------------------------------------
extern "C" void kernel_launch(void* const* d_in, const int* in_sizes, int n_in,
                              void* d_out, int out_size, void* d_ws, size_t ws_size,
                              hipStream_t stream)
{
    const float* x     = (const float*)d_in[0];
    const float* fw    = (const float*)d_in[1];
    const float* fb    = (const float*)d_in[2];
    const float* fu    = (const float*)d_in[3];
    const float* gw    = (const float*)d_in[4];
    const float* gb    = (const float*)d_in[5];
    const float* gu    = (const float*)d_in[6];
    const float* hww   = (const float*)d_in[7];
    const float* hb    = (const float*)d_in[8];
    const float* hu    = (const float*)d_in[9];
    const float* gamma = (const float*)d_in[10];
    float* out = (float*)d_out;

    char* ws = (char*)d_ws;
    float* sig = (float*)ws;
    unsigned short* Khi = (unsigned short*)(ws + 1024);
    unsigned short* Klo = Khi + (size_t)kB * kHW * 32;
    unsigned short* Qhi = Klo + (size_t)kB * kHW * 32;
    unsigned short* Qlo = Qhi + (size_t)kB * kHW * 32;
    unsigned short* Vb  = Qlo + (size_t)kB * kHW * 32;   // kB*kC*kHW bf16 = 8 MB

    k_sigma<<<dim3(3), dim3(256), 0, stream>>>(fw, fu, gw, gu, hww, hu, sig);
    k_projkq<<<dim3(64, 4), dim3(256), 0, stream>>>(x, fw, fb, gw, gb, sig,
                                                    Khi, Klo, Qhi, Qlo);
    k_projv<<<dim3(16, 8, 4), dim3(256), 0, stream>>>(x, hww, hb, sig, Vb);
    k_attn<<<dim3(64, 4), dim3(256), 0, stream>>>(x, gamma, Khi, Klo, Qhi, Qlo,
                                                  Vb, out);
}

// Round 2
// 426.782 us; speedup vs baseline: 1.7574x; 1.7574x over previous
//
#include <hip/hip_runtime.h>

// ---------------------------------------------------------------------------
// SAGAN self-attention block, MI355X / gfx950.
// B=4, C=256, H=W=64 (HW=4096), Ck=32.
// k_sigma -> k_projkq + k_projv (fp32 vector, bf16 out) -> k_attn
// k_attn v2: async double-buffered V-in-LDS (global_load_lds, XOR swizzle),
// register-pipelined Q, one barrier per tile (no vmcnt drain mid-tile).
// ---------------------------------------------------------------------------

constexpr int kC   = 256;
constexpr int kHW  = 4096;
constexpr int kB   = 4;
constexpr int kCHW = kC * kHW;          // 1048576 per batch

typedef short bf16x8 __attribute__((ext_vector_type(8)));
typedef float f32x4  __attribute__((ext_vector_type(4)));
typedef unsigned short u16;

__device__ __forceinline__ u16 f2bf(float f) {
    union { float f; unsigned u; } v; v.f = f;
    unsigned u = v.u;
    return (u16)((u + 0x7fffu + ((u >> 16) & 1u)) >> 16);  // RNE
}
__device__ __forceinline__ float bf2f(u16 h) {
    union { unsigned u; float f; } v; v.u = ((unsigned)h) << 16;
    return v.f;
}

// ---------------------------------------------------------------------------
// Kernel 1: inverse spectral norms.  sigma = ||W @ normalize(U @ W)||.
// ---------------------------------------------------------------------------
__global__ __launch_bounds__(256) void k_sigma(
    const float* __restrict__ fw, const float* __restrict__ fu,
    const float* __restrict__ gw, const float* __restrict__ gu,
    const float* __restrict__ hww, const float* __restrict__ hu,
    float* __restrict__ sig)
{
    const int which = blockIdx.x;
    const float* W = which == 0 ? fw : (which == 1 ? gw : hww);
    const float* U = which == 0 ? fu : (which == 1 ? gu : hu);
    const int O = (which == 2) ? 256 : 32;
    const int t = threadIdx.x;

    __shared__ float red[256];
    __shared__ float Vv[256];

    float t1 = 0.f;
    for (int o = 0; o < O; ++o) t1 += U[o] * W[o * 256 + t];

    red[t] = t1 * t1;
    __syncthreads();
    for (int s = 128; s > 0; s >>= 1) { if (t < s) red[t] += red[t + s]; __syncthreads(); }
    const float n1 = sqrtf(red[0]);
    Vv[t] = t1 / fmaxf(n1, 1e-12f);
    __syncthreads();

    float t2 = 0.f;
    if (t < O) {
        for (int i = 0; i < 256; ++i) t2 += W[t * 256 + i] * Vv[i];
    }
    __syncthreads();
    red[t] = t2 * t2;
    __syncthreads();
    for (int s = 128; s > 0; s >>= 1) { if (t < s) red[t] += red[t + s]; __syncthreads(); }
    if (t == 0) {
        const float s2 = red[0];
        const float nrm = sqrtf(s2);
        const float sigma = s2 / fmaxf(nrm, 1e-12f);
        sig[which] = 1.0f / sigma;
    }
}

// ---------------------------------------------------------------------------
// Kernel 2: K and Q projections -> combined hi|lo rows.
// Kc/Qc layout: [b][n][64] shorts = [hi d0..31 | lo d0..31]; one 128B row per n.
// ---------------------------------------------------------------------------
__global__ __launch_bounds__(256) void k_projkq(
    const float* __restrict__ x,
    const float* __restrict__ fw, const float* __restrict__ fb,
    const float* __restrict__ gw, const float* __restrict__ gb,
    const float* __restrict__ sig,
    u16* __restrict__ Kc, u16* __restrict__ Qc)
{
    __shared__ float wT[2][256][32];   // [mat][c][d], 64 KB
    const int t = threadIdx.x;
    const int b = blockIdx.y;
    const float invf = sig[0], invg = sig[1];

    for (int idx = t; idx < 8192; idx += 256) {
        const int cc = idx >> 5, d = idx & 31;
        wT[0][cc][d] = fw[d * 256 + cc] * invf;
        wT[1][cc][d] = gw[d * 256 + cc] * invg;
    }
    __syncthreads();

    const int part = t >> 6, nl = t & 63;
    const int mat = part >> 1;
    const int dh = (part & 1) * 16;
    const int n = blockIdx.x * 64 + nl;
    const float* bias = mat ? gb : fb;

    float acc[16];
#pragma unroll
    for (int i = 0; i < 16; ++i) acc[i] = bias[dh + i];

    const float* xp = x + (size_t)b * kCHW + n;
#pragma unroll 2
    for (int cc = 0; cc < 256; ++cc) {
        const float xv = xp[(size_t)cc * kHW];
        const float4* wr = (const float4*)&wT[mat][cc][dh];
        const float4 w0 = wr[0], w1 = wr[1], w2 = wr[2], w3 = wr[3];
        acc[0]  += w0.x * xv; acc[1]  += w0.y * xv; acc[2]  += w0.z * xv; acc[3]  += w0.w * xv;
        acc[4]  += w1.x * xv; acc[5]  += w1.y * xv; acc[6]  += w1.z * xv; acc[7]  += w1.w * xv;
        acc[8]  += w2.x * xv; acc[9]  += w2.y * xv; acc[10] += w2.z * xv; acc[11] += w2.w * xv;
        acc[12] += w3.x * xv; acc[13] += w3.y * xv; acc[14] += w3.z * xv; acc[15] += w3.w * xv;
    }

    unsigned ph[8], pl[8];
#pragma unroll
    for (int i = 0; i < 8; ++i) {
        const u16 h0 = f2bf(acc[2 * i]);
        const u16 h1 = f2bf(acc[2 * i + 1]);
        const u16 l0 = f2bf(acc[2 * i] - bf2f(h0));
        const u16 l1 = f2bf(acc[2 * i + 1] - bf2f(h1));
        ph[i] = (unsigned)h0 | ((unsigned)h1 << 16);
        pl[i] = (unsigned)l0 | ((unsigned)l1 << 16);
    }
    u16* Hc = mat ? Qc : Kc;
    const size_t off = (size_t)(b * kHW + n) * 64 + dh;
    *(uint4*)(Hc + off)          = make_uint4(ph[0], ph[1], ph[2], ph[3]);
    *(uint4*)(Hc + off + 8)      = make_uint4(ph[4], ph[5], ph[6], ph[7]);
    *(uint4*)(Hc + off + 32)     = make_uint4(pl[0], pl[1], pl[2], pl[3]);
    *(uint4*)(Hc + off + 40)     = make_uint4(pl[4], pl[5], pl[6], pl[7]);
}

// ---------------------------------------------------------------------------
// Kernel 3: V projection.  Output bf16 in [b][c][m] layout (m contiguous).
// ---------------------------------------------------------------------------
__global__ __launch_bounds__(256) void k_projv(
    const float* __restrict__ x,
    const float* __restrict__ hww, const float* __restrict__ hb,
    const float* __restrict__ sig,
    u16* __restrict__ Vb)
{
    __shared__ float wT[256][32];
    const int t = threadIdx.x;
    const int mt = blockIdx.x, cg = blockIdx.y, b = blockIdx.z;
    const float invh = sig[2];

    for (int idx = t; idx < 8192; idx += 256) {
        const int cc = idx >> 5, i = idx & 31;
        wT[cc][i] = hww[(size_t)(cg * 32 + i) * 256 + cc] * invh;
    }
    __syncthreads();

    const int m = mt * 256 + t;
    float acc[32];
#pragma unroll
    for (int i = 0; i < 32; ++i) acc[i] = hb[cg * 32 + i];

    const float* xp = x + (size_t)b * kCHW + m;
#pragma unroll 2
    for (int cc = 0; cc < 256; ++cc) {
        const float xv = xp[(size_t)cc * kHW];
        const float4* wr = (const float4*)&wT[cc][0];
#pragma unroll
        for (int k4 = 0; k4 < 8; ++k4) {
            const float4 w = wr[k4];
            acc[k4 * 4 + 0] += w.x * xv;
            acc[k4 * 4 + 1] += w.y * xv;
            acc[k4 * 4 + 2] += w.z * xv;
            acc[k4 * 4 + 3] += w.w * xv;
        }
    }

    const size_t base = ((size_t)b * kC + cg * 32) * kHW + m;
#pragma unroll
    for (int i = 0; i < 32; ++i) Vb[base + (size_t)i * kHW] = f2bf(acc[i]);
}

// ---------------------------------------------------------------------------
// Kernel 4: flash attention, async-pipelined.
// grid (64 row-tiles, 4 b), 256 thr (4 waves), 16 rows/wave.
// V tile (256c x 64m, 32 KB) staged per block via global_load_lds,
// double-buffered, chunk XOR-swizzle (phys = j ^ (c&7)) -> 2-way-only LDS
// bank aliasing on the B-fragment ds_read_b128 without padding.
// Q fragments register-pipelined one tile ahead. P is wave-private (no
// cross-wave barrier needed). One s_waitcnt vmcnt(0)+s_barrier per tile.
// ---------------------------------------------------------------------------
__global__ __launch_bounds__(256, 1) void k_attn(
    const float* __restrict__ x, const float* __restrict__ gamma,
    const u16* __restrict__ Kc, const u16* __restrict__ Qc,
    const u16* __restrict__ Vb,
    float* __restrict__ out)
{
    __shared__ __align__(16) u16 Vt[2][16384];   // 2 x 32 KB, swizzled [c][m]
    __shared__ __align__(16) u16 Pt[4][16 * 72]; // 9 KB, per-wave P tiles

    const int t = threadIdx.x;
    const int wave = t >> 6, lane = t & 63;
    const int quad = lane >> 4, l15 = lane & 15;
    const int b = blockIdx.y;
    const int nb = blockIdx.x * 64 + wave * 16;

    const u16* Kb  = Kc + (size_t)b * kHW * 64;
    const u16* Qb  = Qc + (size_t)b * kHW * 64;
    const u16* Vbb = Vb + (size_t)b * kC * kHW;

    // K fragments (hi|lo) for this wave's 16 rows
    const size_t krow = (size_t)(nb + l15) * 64 + quad * 8;
    const bf16x8 kh = *(const bf16x8*)(Kb + krow);
    const bf16x8 kl = *(const bf16x8*)(Kb + krow + 32);

    // V staging lane constants: instr i covers c rows wave*64+i*8 .. +7.
    // lane l -> c = wave*64 + i*8 + (l>>3), phys chunk p = l&7,
    // logical chunk j = p ^ (c&7)  (c&7 == (l>>3)&7).
    const int srow = (lane >> 3) & 7;
    const size_t vg_base = (size_t)(wave * 64 + srow) * kHW
                         + (size_t)(((lane & 7) ^ srow) << 3);

    f32x4 O[16] = {};
    float mrow[4] = { -1e30f, -1e30f, -1e30f, -1e30f };
    float lrow[4] = { 0.f, 0.f, 0.f, 0.f };
    u16* myP = Pt[wave];

    // ---- prologue: stage V tile 0, load Q frags tile 0 ----
#pragma unroll
    for (int i = 0; i < 8; ++i)
        __builtin_amdgcn_global_load_lds(
            (const __attribute__((address_space(1))) void*)(Vbb + vg_base + (size_t)i * 8 * kHW),
            (__attribute__((address_space(3))) void*)&Vt[0][(wave * 8 + i) * 512],
            16, 0, 0);

    bf16x8 qh[4], ql[4];
#pragma unroll
    for (int mi = 0; mi < 4; ++mi) {
        const size_t qoff = (size_t)(mi * 16 + l15) * 64 + quad * 8;
        qh[mi] = *(const bf16x8*)(Qb + qoff);
        ql[mi] = *(const bf16x8*)(Qb + qoff + 32);
    }
    asm volatile("s_waitcnt vmcnt(0)\n\ts_barrier" ::: "memory");

    for (int mt = 0; mt < 64; ++mt) {
        const int cur = mt & 1;
        const int m0 = mt * 64;

        // ---- issue async prefetch of next V tile into other buffer ----
        if (mt < 63) {
#pragma unroll
            for (int i = 0; i < 8; ++i)
                __builtin_amdgcn_global_load_lds(
                    (const __attribute__((address_space(1))) void*)(Vbb + vg_base + (size_t)i * 8 * kHW + m0 + 64),
                    (__attribute__((address_space(3))) void*)&Vt[cur ^ 1][(wave * 8 + i) * 512],
                    16, 0, 0);
        }
        // ---- prefetch next Q fragments into registers ----
        bf16x8 qh2[4], ql2[4];
        const int m0n = (mt < 63) ? m0 + 64 : m0;
#pragma unroll
        for (int mi = 0; mi < 4; ++mi) {
            const size_t qoff = (size_t)(m0n + mi * 16 + l15) * 64 + quad * 8;
            qh2[mi] = *(const bf16x8*)(Qb + qoff);
            ql2[mi] = *(const bf16x8*)(Qb + qoff + 32);
        }

        // ---- scores: S (16 rows x 64 cols), fp32-accurate via hi/lo split ----
        f32x4 s[4];
#pragma unroll
        for (int mi = 0; mi < 4; ++mi) {
            f32x4 acc = { 0.f, 0.f, 0.f, 0.f };
            acc = __builtin_amdgcn_mfma_f32_16x16x32_bf16(kl, qh[mi], acc, 0, 0, 0);
            acc = __builtin_amdgcn_mfma_f32_16x16x32_bf16(kh, ql[mi], acc, 0, 0, 0);
            acc = __builtin_amdgcn_mfma_f32_16x16x32_bf16(kh, qh[mi], acc, 0, 0, 0);
            s[mi] = acc;
        }

        // ---- online softmax row stats ----
        float alpha[4];
#pragma unroll
        for (int r = 0; r < 4; ++r) {
            float v = fmaxf(fmaxf(s[0][r], s[1][r]), fmaxf(s[2][r], s[3][r]));
            v = fmaxf(v, __shfl_xor(v, 1));
            v = fmaxf(v, __shfl_xor(v, 2));
            v = fmaxf(v, __shfl_xor(v, 4));
            v = fmaxf(v, __shfl_xor(v, 8));
            const float mnew = fmaxf(mrow[r], v);
            alpha[r] = __expf(mrow[r] - mnew);
            mrow[r] = mnew;
            float rs = 0.f;
#pragma unroll
            for (int mi = 0; mi < 4; ++mi) {
                const float p = __expf(s[mi][r] - mnew);
                s[mi][r] = p;
                rs += p;
            }
            rs += __shfl_xor(rs, 1);
            rs += __shfl_xor(rs, 2);
            rs += __shfl_xor(rs, 4);
            rs += __shfl_xor(rs, 8);
            lrow[r] = lrow[r] * alpha[r] + rs;
        }

        // ---- rescale O ----
#pragma unroll
        for (int ct = 0; ct < 16; ++ct) {
#pragma unroll
            for (int r = 0; r < 4; ++r) O[ct][r] *= alpha[r];
        }

        // ---- P: C-layout -> A-layout via wave-private LDS (no barrier) ----
#pragma unroll
        for (int mi = 0; mi < 4; ++mi) {
#pragma unroll
            for (int r = 0; r < 4; ++r) {
                myP[(quad * 4 + r) * 72 + mi * 16 + l15] = f2bf(s[mi][r]);
            }
        }
        // compiler inserts lgkmcnt wait for the same-wave ds_read below

        // ---- PV: O(16x256) += P(16x64) @ V^T(64x256), V from LDS ----
#pragma unroll
        for (int ks = 0; ks < 2; ++ks) {
            const bf16x8 pa = *(const bf16x8*)(myP + l15 * 72 + ks * 32 + quad * 8);
            const int vbase = l15 * 64 + (((ks * 4 + quad) ^ (l15 & 7)) << 3);
#pragma unroll
            for (int ct = 0; ct < 16; ++ct) {
                const bf16x8 vb8 = *(const bf16x8*)(&Vt[cur][ct * 1024 + vbase]);
                O[ct] = __builtin_amdgcn_mfma_f32_16x16x32_bf16(pa, vb8, O[ct], 0, 0, 0);
            }
        }

#pragma unroll
        for (int mi = 0; mi < 4; ++mi) { qh[mi] = qh2[mi]; ql[mi] = ql2[mi]; }

        // tile-end: drain prefetch (had a full tile of latency cover) + barrier
        asm volatile("s_waitcnt vmcnt(0)\n\ts_barrier" ::: "memory");
    }

    // ---- epilogue: normalize, gamma * out + x ----
    const float g = gamma[0];
    float invl[4];
#pragma unroll
    for (int r = 0; r < 4; ++r) invl[r] = 1.0f / lrow[r];

#pragma unroll
    for (int ct = 0; ct < 16; ++ct) {
#pragma unroll
        for (int r = 0; r < 4; ++r) {
            const int n = nb + quad * 4 + r;
            const int c = ct * 16 + l15;
            const size_t idx = (size_t)b * kCHW + (size_t)n * 256 + c;
            out[idx] = g * (O[ct][r] * invl[r]) + x[idx];
        }
    }
}

// ---------------------------------------------------------------------------
extern "C" void kernel_launch(void* const* d_in, const int* in_sizes, int n_in,
                              void* d_out, int out_size, void* d_ws, size_t ws_size,
                              hipStream_t stream)
{
    const float* x     = (const float*)d_in[0];
    const float* fw    = (const float*)d_in[1];
    const float* fb    = (const float*)d_in[2];
    const float* fu    = (const float*)d_in[3];
    const float* gw    = (const float*)d_in[4];
    const float* gb    = (const float*)d_in[5];
    const float* gu    = (const float*)d_in[6];
    const float* hww   = (const float*)d_in[7];
    const float* hb    = (const float*)d_in[8];
    const float* hu    = (const float*)d_in[9];
    const float* gamma = (const float*)d_in[10];
    float* out = (float*)d_out;

    char* ws = (char*)d_ws;
    float* sig = (float*)ws;
    u16* Kc = (u16*)(ws + 1024);                  // [b][n][64] hi|lo, 2 MB
    u16* Qc = Kc + (size_t)kB * kHW * 64;         // 2 MB
    u16* Vb = Qc + (size_t)kB * kHW * 64;         // [b][c][m], 8 MB

    k_sigma<<<dim3(3), dim3(256), 0, stream>>>(fw, fu, gw, gu, hww, hu, sig);
    k_projkq<<<dim3(64, 4), dim3(256), 0, stream>>>(x, fw, fb, gw, gb, sig, Kc, Qc);
    k_projv<<<dim3(16, 8, 4), dim3(256), 0, stream>>>(x, hww, hb, sig, Vb);
    k_attn<<<dim3(64, 4), dim3(256), 0, stream>>>(x, gamma, Kc, Qc, Vb, out);
}

// Round 3
// 353.536 us; speedup vs baseline: 2.1215x; 1.2072x over previous
//
#include <hip/hip_runtime.h>

// ---------------------------------------------------------------------------
// SAGAN self-attention block, MI355X / gfx950.
// B=4, C=256, H=W=64 (HW=4096), Ck=32.
// v3: transposed-score flash attention (lane-per-row stats, 4 shfl/tile),
// channel-split PV (V LDS reads 4x down, wave-private V slices), single
// __syncthreads per tile, LDS-staged projections.
// ---------------------------------------------------------------------------

constexpr int kC   = 256;
constexpr int kHW  = 4096;
constexpr int kB   = 4;
constexpr int kCHW = kC * kHW;

typedef short bf16x8 __attribute__((ext_vector_type(8)));
typedef float f32x4  __attribute__((ext_vector_type(4)));
typedef unsigned short u16;

__device__ __forceinline__ u16 f2bf(float f) {
    union { float f; unsigned u; } v; v.f = f;
    unsigned u = v.u;
    return (u16)((u + 0x7fffu + ((u >> 16) & 1u)) >> 16);  // RNE
}
__device__ __forceinline__ float bf2f(u16 h) {
    union { unsigned u; float f; } v; v.u = ((unsigned)h) << 16;
    return v.f;
}

// ---------------------------------------------------------------------------
// Kernel 1: inverse spectral norms, 1024 threads/block, 3 blocks.
// sigma = ||W V||^2 / max(||W V||, eps), V = normalize(U W).  sig = 1/sigma.
// ---------------------------------------------------------------------------
__global__ __launch_bounds__(1024) void k_sigma(
    const float* __restrict__ fw, const float* __restrict__ fu,
    const float* __restrict__ gw, const float* __restrict__ gu,
    const float* __restrict__ hww, const float* __restrict__ hu,
    float* __restrict__ sig)
{
    const int which = blockIdx.x;
    const float* W = which == 0 ? fw : (which == 1 ? gw : hww);
    const float* U = which == 0 ? fu : (which == 1 ? gu : hu);
    const int O = (which == 2) ? 256 : 32;
    const int t = threadIdx.x;

    __shared__ float par[4][256];
    __shared__ float red[256];
    __shared__ __align__(16) float Vv[256];

    // phase 1: t1[i] = sum_o U[o] W[o,i], o split 4 ways
    {
        const int i = t & 255, och = t >> 8;
        int olim = O - och * 64; olim = olim < 0 ? 0 : (olim > 64 ? 64 : olim);
        float p = 0.f;
        for (int oo = 0; oo < olim; ++oo) {
            const int o = och * 64 + oo;
            p += U[o] * W[o * 256 + i];
        }
        par[och][i] = p;
    }
    __syncthreads();
    float t1 = 0.f;
    if (t < 256) {
        t1 = par[0][t] + par[1][t] + par[2][t] + par[3][t];
        red[t] = t1 * t1;
    }
    __syncthreads();
    for (int s = 128; s > 0; s >>= 1) { if (t < s) red[t] += red[t + s]; __syncthreads(); }
    if (t < 256) Vv[t] = t1 / fmaxf(sqrtf(red[0]), 1e-12f);
    __syncthreads();

    // phase 2: t2[o] = sum_i W[o,i] V[i], i split 4 ways, float4
    {
        const int o = t & 255, ich = t >> 8;
        float q = 0.f;
        if (o < O) {
            const float4* Wr = (const float4*)(W + (size_t)o * 256 + ich * 64);
            const float4* Vr = (const float4*)(&Vv[ich * 64]);
#pragma unroll
            for (int j = 0; j < 16; ++j) {
                const float4 w = Wr[j]; const float4 v = Vr[j];
                q += w.x * v.x + w.y * v.y + w.z * v.z + w.w * v.w;
            }
        }
        par[ich][o] = q;
    }
    __syncthreads();
    if (t < 256) {
        const float t2 = par[0][t] + par[1][t] + par[2][t] + par[3][t];
        red[t] = t2 * t2;
    }
    __syncthreads();
    for (int s = 128; s > 0; s >>= 1) { if (t < s) red[t] += red[t + s]; __syncthreads(); }
    if (t == 0) {
        const float s2 = red[0];
        sig[which] = fmaxf(sqrtf(s2), 1e-12f) / s2;   // 1/sigma
    }
}

// ---------------------------------------------------------------------------
// Kernel 2: K/Q projection, one matrix per blockIdx.z.  LDS-staged x tile.
// Output rows [b][n][64] shorts = [hi d0..31 | lo d0..31].
// ---------------------------------------------------------------------------
__global__ __launch_bounds__(256) void k_projkq(
    const float* __restrict__ x,
    const float* __restrict__ fw, const float* __restrict__ fb,
    const float* __restrict__ gw, const float* __restrict__ gb,
    const float* __restrict__ sig,
    u16* __restrict__ Kc, u16* __restrict__ Qc)
{
    __shared__ float wT[256][36];              // [c_in][d], padded stride
    __shared__ __align__(16) float xs[256][64]; // [c_in][n]
    const int t = threadIdx.x;
    const int b = blockIdx.y, mat = blockIdx.z;
    const int n0 = blockIdx.x * 64;
    const float inv = sig[mat];
    const float* wsrc = mat ? gw : fw;
    const float* bias = mat ? gb : fb;

    // stage x tile via global_load_lds (lane-linear dst)
    const int wv = t >> 6, ln = t & 63;
    const float* xg = x + (size_t)b * kCHW + (size_t)(wv * 64 + (ln >> 4)) * kHW
                    + n0 + (ln & 15) * 4;
#pragma unroll
    for (int i = 0; i < 16; ++i)
        __builtin_amdgcn_global_load_lds(
            (const __attribute__((address_space(1))) void*)(xg + (size_t)i * 4 * kHW),
            (__attribute__((address_space(3))) void*)&xs[wv * 64 + i * 4][0],
            16, 0, 0);

    // stage weights: coalesced global reads (lanes vary c_in)
    for (int idx = t; idx < 8192; idx += 256) {
        const int cc = idx & 255, d = idx >> 8;
        wT[cc][d] = wsrc[d * 256 + cc] * inv;
    }
    __syncthreads();

    const int nl = t & 63, dq = t >> 6;   // thread: 1 n, 8 d's
    float acc[8];
#pragma unroll
    for (int i = 0; i < 8; ++i) acc[i] = bias[dq * 8 + i];

#pragma unroll 4
    for (int cc = 0; cc < 256; ++cc) {
        const float xv = xs[cc][nl];
        const float4 w0 = *(const float4*)&wT[cc][dq * 8];
        const float4 w1 = *(const float4*)&wT[cc][dq * 8 + 4];
        acc[0] += w0.x * xv; acc[1] += w0.y * xv; acc[2] += w0.z * xv; acc[3] += w0.w * xv;
        acc[4] += w1.x * xv; acc[5] += w1.y * xv; acc[6] += w1.z * xv; acc[7] += w1.w * xv;
    }

    unsigned ph[4], pl[4];
#pragma unroll
    for (int i = 0; i < 4; ++i) {
        const u16 h0 = f2bf(acc[2 * i]);
        const u16 h1 = f2bf(acc[2 * i + 1]);
        const u16 l0 = f2bf(acc[2 * i] - bf2f(h0));
        const u16 l1 = f2bf(acc[2 * i + 1] - bf2f(h1));
        ph[i] = (unsigned)h0 | ((unsigned)h1 << 16);
        pl[i] = (unsigned)l0 | ((unsigned)l1 << 16);
    }
    u16* H = mat ? Qc : Kc;
    const size_t off = (size_t)(b * kHW + n0 + nl) * 64;
    *(uint4*)(H + off + dq * 8)      = make_uint4(ph[0], ph[1], ph[2], ph[3]);
    *(uint4*)(H + off + 32 + dq * 8) = make_uint4(pl[0], pl[1], pl[2], pl[3]);
}

// ---------------------------------------------------------------------------
// Kernel 3: V projection.  LDS-staged x tile, c_out groups looped.
// Output bf16 [b][c][m], m contiguous.
// ---------------------------------------------------------------------------
__global__ __launch_bounds__(256) void k_projv(
    const float* __restrict__ x,
    const float* __restrict__ hww, const float* __restrict__ hb,
    const float* __restrict__ sig,
    u16* __restrict__ Vb)
{
    __shared__ float wv2[256][36];
    __shared__ __align__(16) float xs[256][64];
    const int t = threadIdx.x;
    const int b = blockIdx.y;
    const int m0 = blockIdx.x * 64;
    const float inv = sig[2];

    const int wv = t >> 6, ln = t & 63;
    const float* xg = x + (size_t)b * kCHW + (size_t)(wv * 64 + (ln >> 4)) * kHW
                    + m0 + (ln & 15) * 4;
#pragma unroll
    for (int i = 0; i < 16; ++i)
        __builtin_amdgcn_global_load_lds(
            (const __attribute__((address_space(1))) void*)(xg + (size_t)i * 4 * kHW),
            (__attribute__((address_space(3))) void*)&xs[wv * 64 + i * 4][0],
            16, 0, 0);

    const int m = t & 63, co4 = t >> 6;   // thread: 1 m, 8 c_out per group
    for (int cg = 0; cg < 8; ++cg) {
        __syncthreads();   // cg=0: x-stage drain; cg>0: protect prev reads
        for (int idx = t; idx < 8192; idx += 256) {
            const int cc = idx & 255, i = idx >> 8;
            wv2[cc][i] = hww[(size_t)(cg * 32 + i) * 256 + cc] * inv;
        }
        __syncthreads();

        float acc[8];
#pragma unroll
        for (int i = 0; i < 8; ++i) acc[i] = hb[cg * 32 + co4 * 8 + i];

#pragma unroll 4
        for (int cc = 0; cc < 256; ++cc) {
            const float xv = xs[cc][m];
            const float4 w0 = *(const float4*)&wv2[cc][co4 * 8];
            const float4 w1 = *(const float4*)&wv2[cc][co4 * 8 + 4];
            acc[0] += w0.x * xv; acc[1] += w0.y * xv; acc[2] += w0.z * xv; acc[3] += w0.w * xv;
            acc[4] += w1.x * xv; acc[5] += w1.y * xv; acc[6] += w1.z * xv; acc[7] += w1.w * xv;
        }

        const size_t base = ((size_t)b * kC + cg * 32 + co4 * 8) * kHW + m0 + m;
#pragma unroll
        for (int i = 0; i < 8; ++i) Vb[base + (size_t)i * kHW] = f2bf(acc[i]);
    }
}

// ---------------------------------------------------------------------------
// Kernel 4: flash attention v3.  grid (64 row-tiles, 4 b), 256 thr (4 waves).
// Scores transposed: mfma(A=Q, B=K) -> D[row=m][col=n]; lane owns 1 query
// row -> stats = in-lane reduce + 2+2 shfl_xor.  Channel-split PV: wave w
// owns channels [w*64, w*64+64) (its own staged V slice); P shared via LDS
// (double-buffered), ONE __syncthreads per tile.
// ---------------------------------------------------------------------------
__global__ __launch_bounds__(256, 1) void k_attn(
    const float* __restrict__ x, const float* __restrict__ gamma,
    const u16* __restrict__ Kc, const u16* __restrict__ Qc,
    const u16* __restrict__ Vb,
    float* __restrict__ out)
{
    __shared__ __align__(16) u16 Vt[2][16384];      // 64 KB, swizzled [c][m]
    __shared__ __align__(16) u16 Pt[2][4][16 * 72]; // 18 KB, dbuf x rowgroup
    __shared__ __align__(16) float aLDS[2][64];
    __shared__ __align__(16) float lLDS[64];

    const int t = threadIdx.x;
    const int wave = t >> 6, lane = t & 63;
    const int quad = lane >> 4, l15 = lane & 15;
    const int b = blockIdx.y;
    const int nb0 = blockIdx.x * 64;

    const u16* Kb  = Kc + (size_t)b * kHW * 64;
    const u16* Qb  = Qc + (size_t)b * kHW * 64;
    const u16* Vbb = Vb + (size_t)b * kC * kHW;

    // K fragments (B-operand) for this wave's 16 score rows
    const size_t krow = (size_t)(nb0 + wave * 16 + l15) * 64 + quad * 8;
    const bf16x8 kh = *(const bf16x8*)(Kb + krow);
    const bf16x8 kl = *(const bf16x8*)(Kb + krow + 32);

    // V staging: wave stages its own channel slice [wave*64, wave*64+64)
    const int srow = (lane >> 3) & 7;
    const size_t vg_base = (size_t)(wave * 64 + srow) * kHW
                         + (size_t)(((lane & 7) ^ srow) << 3);

    f32x4 O[16] = {};   // [rg][ct]: rows rg*16+quad*4+r, cols wave*64+ct*16+l15
    float mrow = -1e30f, lrow = 0.f;   // per-lane: row l15 of rowgroup `wave`

    // prologue: V tile 0 + Q frags tile 0
#pragma unroll
    for (int i = 0; i < 8; ++i)
        __builtin_amdgcn_global_load_lds(
            (const __attribute__((address_space(1))) void*)(Vbb + vg_base + (size_t)i * 8 * kHW),
            (__attribute__((address_space(3))) void*)&Vt[0][(wave * 8 + i) * 512],
            16, 0, 0);

    bf16x8 qh[4], ql[4];
#pragma unroll
    for (int mi = 0; mi < 4; ++mi) {
        const size_t qoff = (size_t)(mi * 16 + l15) * 64 + quad * 8;
        qh[mi] = *(const bf16x8*)(Qb + qoff);
        ql[mi] = *(const bf16x8*)(Qb + qoff + 32);
    }

    for (int mt = 0; mt < 64; ++mt) {
        const int cur = mt & 1;
        const int m0 = mt * 64;

        // ---- scores: D[row = m (quad*4+r within mi chunk)][col = n (l15)] ----
        f32x4 s[4];
#pragma unroll
        for (int mi = 0; mi < 4; ++mi) {
            f32x4 acc = { 0.f, 0.f, 0.f, 0.f };
            acc = __builtin_amdgcn_mfma_f32_16x16x32_bf16(qh[mi], kl, acc, 0, 0, 0);
            acc = __builtin_amdgcn_mfma_f32_16x16x32_bf16(ql[mi], kh, acc, 0, 0, 0);
            acc = __builtin_amdgcn_mfma_f32_16x16x32_bf16(qh[mi], kh, acc, 0, 0, 0);
            s[mi] = acc;
        }

        // ---- per-lane stats for query row n = l15 (quads hold m-chunks) ----
        float lmax = s[0][0];
#pragma unroll
        for (int mi = 0; mi < 4; ++mi)
#pragma unroll
            for (int r = 0; r < 4; ++r) lmax = fmaxf(lmax, s[mi][r]);
        lmax = fmaxf(lmax, __shfl_xor(lmax, 16));
        lmax = fmaxf(lmax, __shfl_xor(lmax, 32));
        const float mnew = fmaxf(mrow, lmax);
        const float alpha = __expf(mrow - mnew);
        float rs = 0.f;
#pragma unroll
        for (int mi = 0; mi < 4; ++mi)
#pragma unroll
            for (int r = 0; r < 4; ++r) {
                const float p = __expf(s[mi][r] - mnew);
                s[mi][r] = p;
                rs += p;
            }
        rs += __shfl_xor(rs, 16);
        rs += __shfl_xor(rs, 32);
        lrow = lrow * alpha + rs;
        mrow = mnew;

        // ---- write P (A-layout rows) + alpha; v_perm truncation pack ----
        u16* Pw = &Pt[cur][wave][0];
#pragma unroll
        for (int mi = 0; mi < 4; ++mi) {
            const unsigned d0 = __builtin_amdgcn_perm(
                __float_as_uint(s[mi][1]), __float_as_uint(s[mi][0]), 0x07060302u);
            const unsigned d1 = __builtin_amdgcn_perm(
                __float_as_uint(s[mi][3]), __float_as_uint(s[mi][2]), 0x07060302u);
            *(uint2*)(Pw + l15 * 72 + mi * 16 + quad * 4) = make_uint2(d0, d1);
        }
        aLDS[cur][wave * 16 + l15] = alpha;

        __syncthreads();   // the only barrier per tile

        // ---- issue next-tile Q loads + V prefetch (wave-private slice) ----
        if (mt < 63) {
            const int m0n = m0 + 64;
#pragma unroll
            for (int mi = 0; mi < 4; ++mi) {
                const size_t qoff = (size_t)(m0n + mi * 16 + l15) * 64 + quad * 8;
                qh[mi] = *(const bf16x8*)(Qb + qoff);
                ql[mi] = *(const bf16x8*)(Qb + qoff + 32);
            }
#pragma unroll
            for (int i = 0; i < 8; ++i)
                __builtin_amdgcn_global_load_lds(
                    (const __attribute__((address_space(1))) void*)(Vbb + vg_base + (size_t)i * 8 * kHW + m0n),
                    (__attribute__((address_space(3))) void*)&Vt[cur ^ 1][(wave * 8 + i) * 512],
                    16, 0, 0);
        }

        // ---- rescale O by per-row alphas (broadcast from LDS) ----
#pragma unroll
        for (int rg = 0; rg < 4; ++rg) {
            const float4 af = *(const float4*)&aLDS[cur][rg * 16 + quad * 4];
#pragma unroll
            for (int ct = 0; ct < 4; ++ct) {
                O[rg * 4 + ct][0] *= af.x;
                O[rg * 4 + ct][1] *= af.y;
                O[rg * 4 + ct][2] *= af.z;
                O[rg * 4 + ct][3] *= af.w;
            }
        }

        // ---- PV: O(64 rows x 64 ch) += P(64x64) @ V^T(64 x 64 ch) ----
#pragma unroll
        for (int ks = 0; ks < 2; ++ks) {
            const int vcol = ((ks * 4 + quad) ^ (l15 & 7)) << 3;
            bf16x8 vb[4];
#pragma unroll
            for (int ct = 0; ct < 4; ++ct)
                vb[ct] = *(const bf16x8*)&Vt[cur][wave * 4096 + ct * 1024 + l15 * 64 + vcol];
#pragma unroll
            for (int rg = 0; rg < 4; ++rg) {
                const bf16x8 pa = *(const bf16x8*)(&Pt[cur][rg][0] + l15 * 72 + ks * 32 + quad * 8);
#pragma unroll
                for (int ct = 0; ct < 4; ++ct)
                    O[rg * 4 + ct] = __builtin_amdgcn_mfma_f32_16x16x32_bf16(pa, vb[ct], O[rg * 4 + ct], 0, 0, 0);
            }
        }
    }

    // ---- epilogue ----
    lLDS[wave * 16 + l15] = lrow;
    __syncthreads();
    const float g = gamma[0];
#pragma unroll
    for (int rg = 0; rg < 4; ++rg) {
        const float4 lf = *(const float4*)&lLDS[rg * 16 + quad * 4];
        const float4 il = { 1.f / lf.x, 1.f / lf.y, 1.f / lf.z, 1.f / lf.w };
#pragma unroll
        for (int ct = 0; ct < 4; ++ct) {
#pragma unroll
            for (int r = 0; r < 4; ++r) {
                const int n = nb0 + rg * 16 + quad * 4 + r;
                const int c = wave * 64 + ct * 16 + l15;
                const size_t idx = (size_t)b * kCHW + (size_t)n * 256 + c;
                const float iv = r == 0 ? il.x : (r == 1 ? il.y : (r == 2 ? il.z : il.w));
                out[idx] = g * (O[rg * 4 + ct][r] * iv) + x[idx];
            }
        }
    }
}

// ---------------------------------------------------------------------------
extern "C" void kernel_launch(void* const* d_in, const int* in_sizes, int n_in,
                              void* d_out, int out_size, void* d_ws, size_t ws_size,
                              hipStream_t stream)
{
    const float* x     = (const float*)d_in[0];
    const float* fw    = (const float*)d_in[1];
    const float* fb    = (const float*)d_in[2];
    const float* fu    = (const float*)d_in[3];
    const float* gw    = (const float*)d_in[4];
    const float* gb    = (const float*)d_in[5];
    const float* gu    = (const float*)d_in[6];
    const float* hww   = (const float*)d_in[7];
    const float* hb    = (const float*)d_in[8];
    const float* hu    = (const float*)d_in[9];
    const float* gamma = (const float*)d_in[10];
    float* out = (float*)d_out;

    char* ws = (char*)d_ws;
    float* sig = (float*)ws;
    u16* Kc = (u16*)(ws + 1024);                  // [b][n][64] hi|lo, 2 MB
    u16* Qc = Kc + (size_t)kB * kHW * 64;         // 2 MB
    u16* Vb = Qc + (size_t)kB * kHW * 64;         // [b][c][m], 8 MB

    k_sigma<<<dim3(3), dim3(1024), 0, stream>>>(fw, fu, gw, gu, hww, hu, sig);
    k_projkq<<<dim3(64, 4, 2), dim3(256), 0, stream>>>(x, fw, fb, gw, gb, sig, Kc, Qc);
    k_projv<<<dim3(64, 4), dim3(256), 0, stream>>>(x, hww, hb, sig, Vb);
    k_attn<<<dim3(64, 4), dim3(256), 0, stream>>>(x, gamma, Kc, Qc, Vb, out);
}

// Round 4
// 306.488 us; speedup vs baseline: 2.4471x; 1.1535x over previous
//
#include <hip/hip_runtime.h>

// ---------------------------------------------------------------------------
// SAGAN self-attention block, MI355X / gfx950.
// B=4, C=256, H=W=64 (HW=4096), Ck=32.
// v4: XCD-swizzled grid (batch-local L2), V in registers (prefetched),
// Q via XOR-swizzled LDS, split barriers (lgkm-only for P), 2 blocks/CU.
// Projections unified into one wave-sliced FMA kernel.
// ---------------------------------------------------------------------------

constexpr int kC   = 256;
constexpr int kHW  = 4096;
constexpr int kB   = 4;
constexpr int kCHW = kC * kHW;

typedef short bf16x8 __attribute__((ext_vector_type(8)));
typedef float f32x4  __attribute__((ext_vector_type(4)));
typedef unsigned short u16;

__device__ __forceinline__ u16 f2bf(float f) {
    union { float f; unsigned u; } v; v.f = f;
    unsigned u = v.u;
    return (u16)((u + 0x7fffu + ((u >> 16) & 1u)) >> 16);  // RNE
}
__device__ __forceinline__ float bf2f(u16 h) {
    union { unsigned u; float f; } v; v.u = ((unsigned)h) << 16;
    return v.f;
}

// ---------------------------------------------------------------------------
// Kernel 1: inverse spectral norms (unchanged from r3; ~few µs).
// ---------------------------------------------------------------------------
__global__ __launch_bounds__(1024) void k_sigma(
    const float* __restrict__ fw, const float* __restrict__ fu,
    const float* __restrict__ gw, const float* __restrict__ gu,
    const float* __restrict__ hww, const float* __restrict__ hu,
    float* __restrict__ sig)
{
    const int which = blockIdx.x;
    const float* W = which == 0 ? fw : (which == 1 ? gw : hww);
    const float* U = which == 0 ? fu : (which == 1 ? gu : hu);
    const int O = (which == 2) ? 256 : 32;
    const int t = threadIdx.x;

    __shared__ float par[4][256];
    __shared__ float red[256];
    __shared__ __align__(16) float Vv[256];

    {
        const int i = t & 255, och = t >> 8;
        int olim = O - och * 64; olim = olim < 0 ? 0 : (olim > 64 ? 64 : olim);
        float p = 0.f;
        for (int oo = 0; oo < olim; ++oo) {
            const int o = och * 64 + oo;
            p += U[o] * W[o * 256 + i];
        }
        par[och][i] = p;
    }
    __syncthreads();
    float t1 = 0.f;
    if (t < 256) {
        t1 = par[0][t] + par[1][t] + par[2][t] + par[3][t];
        red[t] = t1 * t1;
    }
    __syncthreads();
    for (int s = 128; s > 0; s >>= 1) { if (t < s) red[t] += red[t + s]; __syncthreads(); }
    if (t < 256) Vv[t] = t1 / fmaxf(sqrtf(red[0]), 1e-12f);
    __syncthreads();

    {
        const int o = t & 255, ich = t >> 8;
        float q = 0.f;
        if (o < O) {
            const float4* Wr = (const float4*)(W + (size_t)o * 256 + ich * 64);
            const float4* Vr = (const float4*)(&Vv[ich * 64]);
#pragma unroll
            for (int j = 0; j < 16; ++j) {
                const float4 w = Wr[j]; const float4 v = Vr[j];
                q += w.x * v.x + w.y * v.y + w.z * v.z + w.w * v.w;
            }
        }
        par[ich][o] = q;
    }
    __syncthreads();
    if (t < 256) {
        const float t2 = par[0][t] + par[1][t] + par[2][t] + par[3][t];
        red[t] = t2 * t2;
    }
    __syncthreads();
    for (int s = 128; s > 0; s >>= 1) { if (t < s) red[t] += red[t + s]; __syncthreads(); }
    if (t == 0) {
        const float s2 = red[0];
        sig[which] = fmaxf(sqrtf(s2), 1e-12f) / s2;   // 1/sigma
    }
}

// ---------------------------------------------------------------------------
// Kernel 2: unified projections.  grid 256 (XCD-swizzled), 640 threads.
// lane = n (64 positions), wave = co-slice of 32: wave0=K(fw), wave1=Q(gw),
// waves2-9 = V channels (wave-2)*32.  x tile in LDS ([ci][n]); weight chunk
// [64 ci][320 co] in LDS read wave-uniform (broadcast, conflict-free).
// Scale by 1/sigma applied at the end (linearity), bias after.
// ---------------------------------------------------------------------------
__global__ __launch_bounds__(640) void k_proj(
    const float* __restrict__ x,
    const float* __restrict__ fw, const float* __restrict__ fb,
    const float* __restrict__ gw, const float* __restrict__ gb,
    const float* __restrict__ hww, const float* __restrict__ hb,
    const float* __restrict__ sig,
    u16* __restrict__ Kc, u16* __restrict__ Qc, u16* __restrict__ Vb)
{
    constexpr int WSTRIDE = 324;                 // padded co-stride (floats)
    __shared__ __align__(16) float xs[256][64];  // 64 KB
    __shared__ __align__(16) float wT[64][WSTRIDE]; // 81 KB

    const int t = threadIdx.x;
    const int wave = t >> 6, lane = t & 63;

    const int id = blockIdx.x;
    const int xcd = id & 7, slot = id >> 3;
    const int b = xcd >> 1;
    const int n0 = ((xcd & 1) * 32 + slot) * 64;

    // ---- stage x tile [256 ci][64 n] via global_load_lds (waves 0-7) ----
    if (wave < 8) {
        const int r4 = lane >> 4, c16 = lane & 15;
#pragma unroll
        for (int j = 0; j < 8; ++j) {
            const int ci = (wave * 8 + j) * 4 + r4;
            __builtin_amdgcn_global_load_lds(
                (const __attribute__((address_space(1))) void*)
                    (x + (size_t)b * kCHW + (size_t)ci * kHW + n0 + c16 * 4),
                (__attribute__((address_space(3))) void*)&xs[(wave * 8 + j) * 4][0],
                16, 0, 0);
        }
    }

    // per-thread weight-staging constants: co consecutive across lanes
    const int co_s = (t >= 320) ? t - 320 : t;
    const int cg0  = (t >= 320) ? 1 : 0;
    const float* wrow = (co_s < 32) ? (fw + co_s * 256)
                       : (co_s < 64) ? (gw + (co_s - 32) * 256)
                                     : (hww + (co_s - 64) * 256);

    float acc[32];
#pragma unroll
    for (int i = 0; i < 32; ++i) acc[i] = 0.f;

    for (int ck = 0; ck < 4; ++ck) {
        __syncthreads();   // ck=0: x ready; ck>0: prev wT reads done
        // stage wT[64 ci][320 co] for ci chunk ck (transposed)
#pragma unroll
        for (int it = 0; it < 8; ++it) {
            const int c4g = cg0 + it * 2;              // 0..15
            const float4 w = *(const float4*)(wrow + ck * 64 + c4g * 4);
            wT[c4g * 4 + 0][co_s] = w.x;
            wT[c4g * 4 + 1][co_s] = w.y;
            wT[c4g * 4 + 2][co_s] = w.z;
            wT[c4g * 4 + 3][co_s] = w.w;
        }
        __syncthreads();

#pragma unroll 4
        for (int ci = 0; ci < 64; ++ci) {
            const float xv = xs[ck * 64 + ci][lane];
            const float* wr = &wT[ci][wave * 32];
#pragma unroll
            for (int j4 = 0; j4 < 8; ++j4) {
                const float4 w = *(const float4*)(wr + j4 * 4);
                acc[j4 * 4 + 0] += w.x * xv;
                acc[j4 * 4 + 1] += w.y * xv;
                acc[j4 * 4 + 2] += w.z * xv;
                acc[j4 * 4 + 3] += w.w * xv;
            }
        }
    }

    // ---- epilogue ----
    if (wave < 2) {
        // K (wave 0) / Q (wave 1): scale + bias, hi/lo split, row write
        const float inv = sig[wave];
        const float* bias = wave ? gb : fb;
        u16* H = wave ? Qc : Kc;
        float v[32];
#pragma unroll
        for (int i = 0; i < 32; ++i) v[i] = acc[i] * inv + bias[i];
        unsigned ph[16], pl[16];
#pragma unroll
        for (int i = 0; i < 16; ++i) {
            const u16 h0 = f2bf(v[2 * i]);
            const u16 h1 = f2bf(v[2 * i + 1]);
            const u16 l0 = f2bf(v[2 * i] - bf2f(h0));
            const u16 l1 = f2bf(v[2 * i + 1] - bf2f(h1));
            ph[i] = (unsigned)h0 | ((unsigned)h1 << 16);
            pl[i] = (unsigned)l0 | ((unsigned)l1 << 16);
        }
        const size_t off = (size_t)(b * kHW + n0 + lane) * 64;
        *(uint4*)(H + off)      = make_uint4(ph[0],  ph[1],  ph[2],  ph[3]);
        *(uint4*)(H + off + 8)  = make_uint4(ph[4],  ph[5],  ph[6],  ph[7]);
        *(uint4*)(H + off + 16) = make_uint4(ph[8],  ph[9],  ph[10], ph[11]);
        *(uint4*)(H + off + 24) = make_uint4(ph[12], ph[13], ph[14], ph[15]);
        *(uint4*)(H + off + 32) = make_uint4(pl[0],  pl[1],  pl[2],  pl[3]);
        *(uint4*)(H + off + 40) = make_uint4(pl[4],  pl[5],  pl[6],  pl[7]);
        *(uint4*)(H + off + 48) = make_uint4(pl[8],  pl[9],  pl[10], pl[11]);
        *(uint4*)(H + off + 56) = make_uint4(pl[12], pl[13], pl[14], pl[15]);
    } else {
        const float inv = sig[2];
        const int cbase = (wave - 2) * 32;
#pragma unroll
        for (int j = 0; j < 32; ++j) {
            const int co = cbase + j;
            Vb[((size_t)b * kC + co) * kHW + n0 + lane] = f2bf(acc[j] * inv + hb[co]);
        }
    }
}

// ---------------------------------------------------------------------------
// Kernel 3: flash attention v4.  grid 256 (XCD-swizzled), 256 thr (4 waves),
// 2 blocks/CU.  Scores transposed (lane-per-row stats).  V in registers
// (wave-private 64-ch slices, prefetched 1 tile ahead).  Q via XOR-swizzled
// LDS tile (staged once per block per tile).  P single-buffer, XOR swizzle.
// Barriers: __syncthreads at tile top (drains prev-tile prefetch, full-tile
// cover) + raw lgkmcnt-only barrier for P visibility (keeps vmem in flight).
// ---------------------------------------------------------------------------
__global__ __launch_bounds__(256, 2) void k_attn(
    const float* __restrict__ x, const float* __restrict__ gamma,
    const u16* __restrict__ Kc, const u16* __restrict__ Qc,
    const u16* __restrict__ Vb,
    float* __restrict__ out)
{
    __shared__ __align__(16) u16 Qt[2][4096];   // 16 KB: [buf][64 m][64] swizzled
    __shared__ __align__(16) u16 Pt[4096];      // 8 KB: [64 n][64 m] swizzled
    __shared__ float aLDS[64];
    __shared__ float lLDS[64];

    const int t = threadIdx.x;
    const int wave = t >> 6, lane = t & 63;
    const int quad = lane >> 4, l15 = lane & 15;

    const int id = blockIdx.x;
    const int xcd = id & 7, slot = id >> 3;
    const int b = xcd >> 1;
    const int nb0 = ((xcd & 1) * 32 + slot) * 64;

    const u16* Kb  = Kc + (size_t)b * kHW * 64;
    const u16* Qb  = Qc + (size_t)b * kHW * 64;
    const u16* Vbb = Vb + (size_t)b * kC * kHW;

    // K fragments (B-operand) for this wave's rowgroup rg = wave
    const size_t krow = (size_t)(nb0 + wave * 16 + l15) * 64 + (size_t)quad * 8;
    const bf16x8 kh = *(const bf16x8*)(Kb + krow);
    const bf16x8 kl = *(const bf16x8*)(Kb + krow + 32);

    // V register-fragment row pointers: col c = wave*64 + ct*16 + l15
    const u16* vrow[4];
#pragma unroll
    for (int ct = 0; ct < 4; ++ct)
        vrow[ct] = Vbb + (size_t)(wave * 64 + ct * 16 + l15) * kHW + quad * 8;

    // Q staging lane constants
    const int qs_row = lane >> 3;      // row within instruction (0..7)
    const int qs_ch  = lane & 7;       // physical chunk

    f32x4 O[16] = {};
    float mrow = -1e30f, lrow = 0.f;

    bf16x8 vc[8], vn[8];

    // ---- prologue: stage Qt[0] (tile 0), V regs tile 0 ----
#pragma unroll
    for (int j = 0; j < 2; ++j) {
        const int rloc = (wave * 2 + j) * 8 + qs_row;
        __builtin_amdgcn_global_load_lds(
            (const __attribute__((address_space(1))) void*)
                (Qb + (size_t)rloc * 64 + ((qs_ch ^ (rloc & 7)) << 3)),
            (__attribute__((address_space(3))) void*)&Qt[0][(wave * 2 + j) * 512],
            16, 0, 0);
    }
#pragma unroll
    for (int ct = 0; ct < 4; ++ct)
#pragma unroll
        for (int ks = 0; ks < 2; ++ks)
            vc[ct * 2 + ks] = *(const bf16x8*)(vrow[ct] + ks * 32);

    for (int mt = 0; mt < 64; ++mt) {
        const int cur = mt & 1;
        const int m0 = mt * 64;

        __syncthreads();   // B1: Qt[cur] visible (vmcnt drain of prev-tile stages)

        // ---- issue next-tile prefetches (drained at NEXT B1: full-tile cover)
        if (mt < 63) {
            const int m0n = m0 + 64;
#pragma unroll
            for (int j = 0; j < 2; ++j) {
                const int rloc = (wave * 2 + j) * 8 + qs_row;
                __builtin_amdgcn_global_load_lds(
                    (const __attribute__((address_space(1))) void*)
                        (Qb + (size_t)(m0n + rloc) * 64 + ((qs_ch ^ (rloc & 7)) << 3)),
                    (__attribute__((address_space(3))) void*)&Qt[cur ^ 1][(wave * 2 + j) * 512],
                    16, 0, 0);
            }
        }
        const int m0v = (mt < 63) ? m0 + 64 : m0;
#pragma unroll
        for (int ct = 0; ct < 4; ++ct)
#pragma unroll
            for (int ks = 0; ks < 2; ++ks)
                vn[ct * 2 + ks] = *(const bf16x8*)(vrow[ct] + m0v + ks * 32);

        // ---- scores: D[row=m][col=n], A = Q from swizzled LDS ----
        f32x4 s[4];
#pragma unroll
        for (int mi = 0; mi < 4; ++mi) {
            const int rbase = (mi * 16 + l15) * 64;
            const bf16x8 qhv = *(const bf16x8*)&Qt[cur][rbase + ((quad       ^ (l15 & 7)) << 3)];
            const bf16x8 qlv = *(const bf16x8*)&Qt[cur][rbase + (((quad + 4) ^ (l15 & 7)) << 3)];
            f32x4 acc = { 0.f, 0.f, 0.f, 0.f };
            acc = __builtin_amdgcn_mfma_f32_16x16x32_bf16(qhv, kl, acc, 0, 0, 0);
            acc = __builtin_amdgcn_mfma_f32_16x16x32_bf16(qlv, kh, acc, 0, 0, 0);
            acc = __builtin_amdgcn_mfma_f32_16x16x32_bf16(qhv, kh, acc, 0, 0, 0);
            s[mi] = acc;
        }

        // ---- per-lane online softmax (row n = wave*16+l15) ----
        float lmax = s[0][0];
#pragma unroll
        for (int mi = 0; mi < 4; ++mi)
#pragma unroll
            for (int r = 0; r < 4; ++r) lmax = fmaxf(lmax, s[mi][r]);
        lmax = fmaxf(lmax, __shfl_xor(lmax, 16));
        lmax = fmaxf(lmax, __shfl_xor(lmax, 32));
        const float mnew = fmaxf(mrow, lmax);
        const float alpha = __expf(mrow - mnew);
        float rs = 0.f;
#pragma unroll
        for (int mi = 0; mi < 4; ++mi)
#pragma unroll
            for (int r = 0; r < 4; ++r) {
                const float p = __expf(s[mi][r] - mnew);
                s[mi][r] = p;
                rs += p;
            }
        rs += __shfl_xor(rs, 16);
        rs += __shfl_xor(rs, 32);
        lrow = lrow * alpha + rs;
        mrow = mnew;

        // ---- write P (row n = wave*16+l15, XOR-swizzled chunks) + alpha ----
        {
            const int prow = wave * 16 + l15;
#pragma unroll
            for (int mi = 0; mi < 4; ++mi) {
                const unsigned d0 = __builtin_amdgcn_perm(
                    __float_as_uint(s[mi][1]), __float_as_uint(s[mi][0]), 0x07060302u);
                const unsigned d1 = __builtin_amdgcn_perm(
                    __float_as_uint(s[mi][3]), __float_as_uint(s[mi][2]), 0x07060302u);
                const int chunk = 2 * mi + (quad >> 1);
                const int off = prow * 64 + ((chunk ^ (l15 & 7)) << 3) + (quad & 1) * 4;
                *(uint2*)(Pt + off) = make_uint2(d0, d1);
            }
            aLDS[wave * 16 + l15] = alpha;
        }

        // B2: P visibility only — does NOT drain vmem (prefetch stays in flight)
        asm volatile("s_waitcnt lgkmcnt(0)\n\ts_barrier" ::: "memory");

        // ---- rescale O by per-row alphas ----
#pragma unroll
        for (int rg = 0; rg < 4; ++rg) {
            const float4 af = *(const float4*)&aLDS[rg * 16 + quad * 4];
#pragma unroll
            for (int ct = 0; ct < 4; ++ct) {
                O[rg * 4 + ct][0] *= af.x;
                O[rg * 4 + ct][1] *= af.y;
                O[rg * 4 + ct][2] *= af.z;
                O[rg * 4 + ct][3] *= af.w;
            }
        }

        // ---- PV: O(64n x 64ch) += P @ V, V from registers ----
#pragma unroll
        for (int ks = 0; ks < 2; ++ks) {
#pragma unroll
            for (int rg = 0; rg < 4; ++rg) {
                const bf16x8 pa = *(const bf16x8*)&Pt[(rg * 16 + l15) * 64
                                     + (((ks * 4 + quad) ^ (l15 & 7)) << 3)];
#pragma unroll
                for (int ct = 0; ct < 4; ++ct)
                    O[rg * 4 + ct] = __builtin_amdgcn_mfma_f32_16x16x32_bf16(
                        pa, vc[ct * 2 + ks], O[rg * 4 + ct], 0, 0, 0);
            }
        }

#pragma unroll
        for (int i = 0; i < 8; ++i) vc[i] = vn[i];
    }

    // ---- epilogue ----
    lLDS[wave * 16 + l15] = lrow;
    __syncthreads();
    const float g = gamma[0];
#pragma unroll
    for (int rg = 0; rg < 4; ++rg) {
        const float4 lf = *(const float4*)&lLDS[rg * 16 + quad * 4];
        const float4 il = { 1.f / lf.x, 1.f / lf.y, 1.f / lf.z, 1.f / lf.w };
#pragma unroll
        for (int ct = 0; ct < 4; ++ct) {
#pragma unroll
            for (int r = 0; r < 4; ++r) {
                const int n = nb0 + rg * 16 + quad * 4 + r;
                const int c = wave * 64 + ct * 16 + l15;
                const size_t idx = (size_t)b * kCHW + (size_t)n * 256 + c;
                const float iv = r == 0 ? il.x : (r == 1 ? il.y : (r == 2 ? il.z : il.w));
                out[idx] = g * (O[rg * 4 + ct][r] * iv) + x[idx];
            }
        }
    }
}

// ---------------------------------------------------------------------------
extern "C" void kernel_launch(void* const* d_in, const int* in_sizes, int n_in,
                              void* d_out, int out_size, void* d_ws, size_t ws_size,
                              hipStream_t stream)
{
    const float* x     = (const float*)d_in[0];
    const float* fw    = (const float*)d_in[1];
    const float* fb    = (const float*)d_in[2];
    const float* fu    = (const float*)d_in[3];
    const float* gw    = (const float*)d_in[4];
    const float* gb    = (const float*)d_in[5];
    const float* gu    = (const float*)d_in[6];
    const float* hww   = (const float*)d_in[7];
    const float* hb    = (const float*)d_in[8];
    const float* hu    = (const float*)d_in[9];
    const float* gamma = (const float*)d_in[10];
    float* out = (float*)d_out;

    char* ws = (char*)d_ws;
    float* sig = (float*)ws;
    u16* Kc = (u16*)(ws + 1024);                  // [b][n][64] hi|lo, 2 MB
    u16* Qc = Kc + (size_t)kB * kHW * 64;         // 2 MB
    u16* Vb = Qc + (size_t)kB * kHW * 64;         // [b][c][m], 8 MB

    k_sigma<<<dim3(3), dim3(1024), 0, stream>>>(fw, fu, gw, gu, hww, hu, sig);
    k_proj<<<dim3(256), dim3(640), 0, stream>>>(x, fw, fb, gw, gb, hww, hb, sig,
                                                Kc, Qc, Vb);
    k_attn<<<dim3(256), dim3(256), 0, stream>>>(x, gamma, Kc, Qc, Vb, out);
}

// Round 5
// 271.254 us; speedup vs baseline: 2.7650x; 1.1299x over previous
//
#include <hip/hip_runtime.h>

// ---------------------------------------------------------------------------
// SAGAN self-attention block, MI355X / gfx950.
// B=4, C=256, H=W=64 (HW=4096), Ck=32.
// v5: k_attn 8 waves (2/SIMD), pair-split scores + 2-level flash stat merge;
// k_proj rewritten as hi/lo-split bf16 MFMA GEMM (W pre-split in k_sigma).
// ---------------------------------------------------------------------------

constexpr int kC   = 256;
constexpr int kHW  = 4096;
constexpr int kB   = 4;
constexpr int kCHW = kC * kHW;

typedef short bf16x8 __attribute__((ext_vector_type(8)));
typedef float f32x4  __attribute__((ext_vector_type(4)));
typedef unsigned short u16;

__device__ __forceinline__ u16 f2bf(float f) {
    union { float f; unsigned u; } v; v.f = f;
    unsigned u = v.u;
    return (u16)((u + 0x7fffu + ((u >> 16) & 1u)) >> 16);  // RNE
}
__device__ __forceinline__ float bf2f(u16 h) {
    union { unsigned u; float f; } v; v.u = ((unsigned)h) << 16;
    return v.f;
}

// ---------------------------------------------------------------------------
// Kernel 1: inverse spectral norms + W -> bf16 hi/lo split (sigma NOT baked).
// wh/wl rows: [0,32) = fw, [32,64) = gw, [64,320) = hww.
// ---------------------------------------------------------------------------
__global__ __launch_bounds__(1024) void k_sigma(
    const float* __restrict__ fw, const float* __restrict__ fu,
    const float* __restrict__ gw, const float* __restrict__ gu,
    const float* __restrict__ hww, const float* __restrict__ hu,
    float* __restrict__ sig, u16* __restrict__ wh, u16* __restrict__ wl)
{
    const int which = blockIdx.x;
    const float* W = which == 0 ? fw : (which == 1 ? gw : hww);
    const float* U = which == 0 ? fu : (which == 1 ? gu : hu);
    const int O = (which == 2) ? 256 : 32;
    const int t = threadIdx.x;

    __shared__ float par[4][256];
    __shared__ float red[256];
    __shared__ __align__(16) float Vv[256];

    {
        const int i = t & 255, och = t >> 8;
        int olim = O - och * 64; olim = olim < 0 ? 0 : (olim > 64 ? 64 : olim);
        float p = 0.f;
        for (int oo = 0; oo < olim; ++oo) {
            const int o = och * 64 + oo;
            p += U[o] * W[o * 256 + i];
        }
        par[och][i] = p;
    }
    __syncthreads();
    float t1 = 0.f;
    if (t < 256) {
        t1 = par[0][t] + par[1][t] + par[2][t] + par[3][t];
        red[t] = t1 * t1;
    }
    __syncthreads();
    for (int s = 128; s > 0; s >>= 1) { if (t < s) red[t] += red[t + s]; __syncthreads(); }
    if (t < 256) Vv[t] = t1 / fmaxf(sqrtf(red[0]), 1e-12f);
    __syncthreads();

    {
        const int o = t & 255, ich = t >> 8;
        float q = 0.f;
        if (o < O) {
            const float4* Wr = (const float4*)(W + (size_t)o * 256 + ich * 64);
            const float4* Vr = (const float4*)(&Vv[ich * 64]);
#pragma unroll
            for (int j = 0; j < 16; ++j) {
                const float4 w = Wr[j]; const float4 v = Vr[j];
                q += w.x * v.x + w.y * v.y + w.z * v.z + w.w * v.w;
            }
        }
        par[ich][o] = q;
    }
    __syncthreads();
    if (t < 256) {
        const float t2 = par[0][t] + par[1][t] + par[2][t] + par[3][t];
        red[t] = t2 * t2;
    }
    __syncthreads();
    for (int s = 128; s > 0; s >>= 1) { if (t < s) red[t] += red[t + s]; __syncthreads(); }
    if (t == 0) {
        const float s2 = red[0];
        sig[which] = fmaxf(sqrtf(s2), 1e-12f) / s2;   // 1/sigma
    }

    // ---- W -> bf16 hi/lo (independent of sigma) ----
    const int nElem = O * 256;
    const int base = (which == 0) ? 0 : (which == 1 ? 32 * 256 : 64 * 256);
    for (int i = t; i < nElem; i += 1024) {
        const float f = W[i];
        const u16 h = f2bf(f);
        wh[base + i] = h;
        wl[base + i] = f2bf(f - bf2f(h));
    }
}

// ---------------------------------------------------------------------------
// Kernel 2: all projections as one MFMA GEMM.  grid (64 n-tiles, 4 b),
// 512 thr (8 waves).  Wave = (nch = wave&3, cohalf = wave>>2).
// out[320 co][64 n] = W[320][256] @ x[256][64], hi/lo-split bf16 MFMA
// (3 MFMAs per tile-K, wl*xl dropped).  x staged fp32 via global_load_lds,
// column-gathered into B-frags (4-way bank conflict, acceptable once).
// K/Q epilogue: fp32 acc * 1/sigma + bias -> hi/lo row [n][64]; V -> bf16.
// ---------------------------------------------------------------------------
__global__ __launch_bounds__(512) void k_proj(
    const float* __restrict__ x,
    const u16* __restrict__ wh, const u16* __restrict__ wl,
    const float* __restrict__ fb, const float* __restrict__ gb,
    const float* __restrict__ hb, const float* __restrict__ sig,
    u16* __restrict__ Kc, u16* __restrict__ Qc, u16* __restrict__ Vb)
{
    __shared__ __align__(16) float xs[256][64];  // 64 KB
    __shared__ float bLDS[320];

    const int t = threadIdx.x;
    const int wave = t >> 6, lane = t & 63;
    const int quad = lane >> 4, l15 = lane & 15;
    const int b = blockIdx.y;
    const int n0 = blockIdx.x * 64;
    const int nch = wave & 3, cohalf = wave >> 2;

    // stage x tile [256 ci][64 n] (8 waves x 8 instrs x 1 KB)
    {
        const int r4i = lane >> 4, c16 = lane & 15;
        const float* xg = x + (size_t)b * kCHW + (size_t)r4i * kHW + n0 + c16 * 4;
#pragma unroll
        for (int j = 0; j < 8; ++j) {
            const int cibase = (wave * 8 + j) * 4;
            __builtin_amdgcn_global_load_lds(
                (const __attribute__((address_space(1))) void*)(xg + (size_t)cibase * kHW),
                (__attribute__((address_space(3))) void*)&xs[cibase][0], 16, 0, 0);
        }
    }
    if (t < 320) bLDS[t] = (t < 32) ? fb[t] : (t < 64) ? gb[t - 32] : hb[t - 64];
    __syncthreads();

    // B-frags (x) hi/lo for 8 ci-slices; lane = col n
    const int n = nch * 16 + l15;
    bf16x8 bh[8], bl[8];
#pragma unroll
    for (int s = 0; s < 8; ++s) {
        union { u16 a[8]; bf16x8 v; } H, L;
#pragma unroll
        for (int j = 0; j < 8; ++j) {
            const float v = xs[s * 32 + quad * 8 + j][n];
            const u16 h = f2bf(v);
            H.a[j] = h; L.a[j] = f2bf(v - bf2f(h));
        }
        bh[s] = H.v; bl[s] = L.v;
    }

    f32x4 acc[10] = {};
#pragma unroll
    for (int c = 0; c < 10; ++c) {
        const size_t wbase = (size_t)((cohalf * 10 + c) * 16 + l15) * 256 + quad * 8;
#pragma unroll
        for (int s = 0; s < 8; ++s) {
            const bf16x8 ah = *(const bf16x8*)(wh + wbase + s * 32);
            const bf16x8 al = *(const bf16x8*)(wl + wbase + s * 32);
            acc[c] = __builtin_amdgcn_mfma_f32_16x16x32_bf16(ah, bh[s], acc[c], 0, 0, 0);
            acc[c] = __builtin_amdgcn_mfma_f32_16x16x32_bf16(ah, bl[s], acc[c], 0, 0, 0);
            acc[c] = __builtin_amdgcn_mfma_f32_16x16x32_bf16(al, bh[s], acc[c], 0, 0, 0);
        }
    }

    const float s0 = sig[0], s1 = sig[1], s2 = sig[2];
#pragma unroll
    for (int c = 0; c < 10; ++c) {
        const int cog0 = (cohalf * 10 + c) * 16;
        const float inv = (cog0 < 32) ? s0 : (cog0 < 64) ? s1 : s2;
#pragma unroll
        for (int r = 0; r < 4; ++r) {
            const int co = cog0 + quad * 4 + r;
            const float v = acc[c][r] * inv + bLDS[co];
            if (co < 64) {
                u16* H = (co < 32) ? Kc : Qc;
                const int d = co & 31;
                const u16 h = f2bf(v);
                const u16 l = f2bf(v - bf2f(h));
                const size_t off = (size_t)(b * kHW + n0 + n) * 64;
                H[off + d] = h;
                H[off + 32 + d] = l;
            } else {
                Vb[((size_t)b * kC + (co - 64)) * kHW + n0 + n] = f2bf(v);
            }
        }
    }
}

// ---------------------------------------------------------------------------
// Kernel 3: flash attention v5.  grid 256 (XCD-swizzled), 512 thr (8 waves,
// 2 waves/SIMD).  Wave = (sg = wave>>1: 16-row group, half = wave&1: m-half).
// Scores: 6 MFMA/wave (2 m-chunks, hi/lo split).  Stats: 2-level flash merge
// across the wave pair via one lgkm barrier.  PV: 32-ch slice/wave, V in
// registers prefetched 1 tile ahead.  Q via XOR-swizzled LDS (dbuf).
// 3 barriers/tile: B1 (full, vmcnt drain of prev-tile stages), Bstat (lgkm),
// BP (lgkm).
// ---------------------------------------------------------------------------
__global__ __launch_bounds__(512, 1) void k_attn(
    const float* __restrict__ x, const float* __restrict__ gamma,
    const u16* __restrict__ Kc, const u16* __restrict__ Qc,
    const u16* __restrict__ Vb,
    float* __restrict__ out)
{
    __shared__ __align__(16) u16 Qt[2][4096];   // 16 KB
    __shared__ __align__(16) u16 Pt[4096];      // 8 KB
    __shared__ float2 stLDS[8][16];
    __shared__ float aLDS[64];
    __shared__ float lLDS[64];

    const int t = threadIdx.x;
    const int wave = t >> 6, lane = t & 63;
    const int quad = lane >> 4, l15 = lane & 15;
    const int sg = wave >> 1, half = wave & 1;

    const int id = blockIdx.x;
    const int xcd = id & 7, slot = id >> 3;
    const int b = xcd >> 1;
    const int nb0 = ((xcd & 1) * 32 + slot) * 64;

    const u16* Kb  = Kc + (size_t)b * kHW * 64;
    const u16* Qb  = Qc + (size_t)b * kHW * 64;
    const u16* Vbb = Vb + (size_t)b * kC * kHW;

    // K B-frags for this wave's 16-row group
    const size_t krow = (size_t)(nb0 + sg * 16 + l15) * 64 + (size_t)quad * 8;
    const bf16x8 kh = *(const bf16x8*)(Kb + krow);
    const bf16x8 kl = *(const bf16x8*)(Kb + krow + 32);

    // V register-fragment row pointers: ch slice = wave*32
    const u16* vrow[2];
#pragma unroll
    for (int ct = 0; ct < 2; ++ct)
        vrow[ct] = Vbb + (size_t)(wave * 32 + ct * 16 + l15) * kHW + quad * 8;

    const int qs_row = lane >> 3, qs_ch = lane & 7;

    f32x4 O[8] = {};
    float mrow = -1e30f, lrow = 0.f;
    bf16x8 vc[4], vn[4];

    // ---- prologue: Qt[0] stage (1 instr/wave), V regs tile 0 ----
    {
        const int rloc = wave * 8 + qs_row;
        __builtin_amdgcn_global_load_lds(
            (const __attribute__((address_space(1))) void*)
                (Qb + (size_t)rloc * 64 + ((qs_ch ^ (rloc & 7)) << 3)),
            (__attribute__((address_space(3))) void*)&Qt[0][wave * 512], 16, 0, 0);
    }
#pragma unroll
    for (int ct = 0; ct < 2; ++ct)
#pragma unroll
        for (int ks = 0; ks < 2; ++ks)
            vc[ct * 2 + ks] = *(const bf16x8*)(vrow[ct] + ks * 32);

    for (int mt = 0; mt < 64; ++mt) {
        const int cur = mt & 1;
        const int m0 = mt * 64;

        __syncthreads();   // B1: Qt[cur] ready (prev-tile stages had full cover)

        if (mt < 63) {
            const int m0n = m0 + 64;
            const int rloc = wave * 8 + qs_row;
            __builtin_amdgcn_global_load_lds(
                (const __attribute__((address_space(1))) void*)
                    (Qb + (size_t)(m0n + rloc) * 64 + ((qs_ch ^ (rloc & 7)) << 3)),
                (__attribute__((address_space(3))) void*)&Qt[cur ^ 1][wave * 512], 16, 0, 0);
        }
        const int m0v = (mt < 63) ? m0 + 64 : m0;
#pragma unroll
        for (int ct = 0; ct < 2; ++ct)
#pragma unroll
            for (int ks = 0; ks < 2; ++ks)
                vn[ct * 2 + ks] = *(const bf16x8*)(vrow[ct] + m0v + ks * 32);

        // ---- scores for this wave's m-half (2 chunks of 16) ----
        f32x4 s[2];
#pragma unroll
        for (int mi2 = 0; mi2 < 2; ++mi2) {
            const int mi = half * 2 + mi2;
            const int rbase = (mi * 16 + l15) * 64;
            const bf16x8 qhv = *(const bf16x8*)&Qt[cur][rbase + ((quad       ^ (l15 & 7)) << 3)];
            const bf16x8 qlv = *(const bf16x8*)&Qt[cur][rbase + (((quad + 4) ^ (l15 & 7)) << 3)];
            f32x4 a = { 0.f, 0.f, 0.f, 0.f };
            a = __builtin_amdgcn_mfma_f32_16x16x32_bf16(qhv, kl, a, 0, 0, 0);
            a = __builtin_amdgcn_mfma_f32_16x16x32_bf16(qlv, kh, a, 0, 0, 0);
            a = __builtin_amdgcn_mfma_f32_16x16x32_bf16(qhv, kh, a, 0, 0, 0);
            s[mi2] = a;
        }

        // ---- wave-local stats over its 32 m (row n = sg*16 + l15) ----
        float lm = s[0][0];
#pragma unroll
        for (int mi2 = 0; mi2 < 2; ++mi2)
#pragma unroll
            for (int r = 0; r < 4; ++r) lm = fmaxf(lm, s[mi2][r]);
        lm = fmaxf(lm, __shfl_xor(lm, 16));
        lm = fmaxf(lm, __shfl_xor(lm, 32));
        float ls = 0.f;
#pragma unroll
        for (int mi2 = 0; mi2 < 2; ++mi2)
#pragma unroll
            for (int r = 0; r < 4; ++r) {
                const float p = __expf(s[mi2][r] - lm);
                s[mi2][r] = p;
                ls += p;
            }
        ls += __shfl_xor(ls, 16);
        ls += __shfl_xor(ls, 32);
        if (lane < 16) stLDS[wave][l15] = make_float2(lm, ls);

        asm volatile("s_waitcnt lgkmcnt(0)\n\ts_barrier" ::: "memory");  // Bstat

        // ---- pair merge (2-level flash) ----
        const float2 o2 = stLDS[wave ^ 1][l15];
        const float mnew = fmaxf(mrow, fmaxf(lm, o2.x));
        const float alpha = __expf(mrow - mnew);
        const float bm = __expf(lm - mnew);
        lrow = lrow * alpha + ls * bm + o2.y * __expf(o2.x - mnew);
        mrow = mnew;

        // ---- scale by bm, pack P (XOR-swizzled), write alpha ----
        {
            const int prow = sg * 16 + l15;
#pragma unroll
            for (int mi2 = 0; mi2 < 2; ++mi2) {
                const float p0 = s[mi2][0] * bm, p1 = s[mi2][1] * bm;
                const float p2 = s[mi2][2] * bm, p3 = s[mi2][3] * bm;
                const unsigned d0 = __builtin_amdgcn_perm(
                    __float_as_uint(p1), __float_as_uint(p0), 0x07060302u);
                const unsigned d1 = __builtin_amdgcn_perm(
                    __float_as_uint(p3), __float_as_uint(p2), 0x07060302u);
                const int mi = half * 2 + mi2;
                const int chunk = 2 * mi + (quad >> 1);
                const int off = prow * 64 + ((chunk ^ (l15 & 7)) << 3) + (quad & 1) * 4;
                *(uint2*)(Pt + off) = make_uint2(d0, d1);
            }
            if (half == 0 && lane < 16) aLDS[sg * 16 + l15] = alpha;
        }

        asm volatile("s_waitcnt lgkmcnt(0)\n\ts_barrier" ::: "memory");  // BP

        // ---- rescale O ----
#pragma unroll
        for (int rg = 0; rg < 4; ++rg) {
            const float4 af = *(const float4*)&aLDS[rg * 16 + quad * 4];
#pragma unroll
            for (int ct = 0; ct < 2; ++ct) {
                O[rg * 2 + ct][0] *= af.x;
                O[rg * 2 + ct][1] *= af.y;
                O[rg * 2 + ct][2] *= af.z;
                O[rg * 2 + ct][3] *= af.w;
            }
        }

        // ---- PV: O(64n x 32ch) += P @ V ----
#pragma unroll
        for (int ks = 0; ks < 2; ++ks) {
#pragma unroll
            for (int rg = 0; rg < 4; ++rg) {
                const bf16x8 pa = *(const bf16x8*)&Pt[(rg * 16 + l15) * 64
                                     + (((ks * 4 + quad) ^ (l15 & 7)) << 3)];
#pragma unroll
                for (int ct = 0; ct < 2; ++ct)
                    O[rg * 2 + ct] = __builtin_amdgcn_mfma_f32_16x16x32_bf16(
                        pa, vc[ct * 2 + ks], O[rg * 2 + ct], 0, 0, 0);
            }
        }

#pragma unroll
        for (int i = 0; i < 4; ++i) vc[i] = vn[i];
    }

    // ---- epilogue ----
    if (half == 0 && lane < 16) lLDS[sg * 16 + l15] = lrow;
    __syncthreads();
    const float g = gamma[0];
#pragma unroll
    for (int rg = 0; rg < 4; ++rg) {
        const float4 lf = *(const float4*)&lLDS[rg * 16 + quad * 4];
        const float4 il = { 1.f / lf.x, 1.f / lf.y, 1.f / lf.z, 1.f / lf.w };
#pragma unroll
        for (int ct = 0; ct < 2; ++ct) {
#pragma unroll
            for (int r = 0; r < 4; ++r) {
                const int nn = nb0 + rg * 16 + quad * 4 + r;
                const int c = wave * 32 + ct * 16 + l15;
                const size_t idx = (size_t)b * kCHW + (size_t)nn * 256 + c;
                const float iv = r == 0 ? il.x : (r == 1 ? il.y : (r == 2 ? il.z : il.w));
                out[idx] = g * (O[rg * 2 + ct][r] * iv) + x[idx];
            }
        }
    }
}

// ---------------------------------------------------------------------------
extern "C" void kernel_launch(void* const* d_in, const int* in_sizes, int n_in,
                              void* d_out, int out_size, void* d_ws, size_t ws_size,
                              hipStream_t stream)
{
    const float* x     = (const float*)d_in[0];
    const float* fw    = (const float*)d_in[1];
    const float* fb    = (const float*)d_in[2];
    const float* fu    = (const float*)d_in[3];
    const float* gw    = (const float*)d_in[4];
    const float* gb    = (const float*)d_in[5];
    const float* gu    = (const float*)d_in[6];
    const float* hww   = (const float*)d_in[7];
    const float* hb    = (const float*)d_in[8];
    const float* hu    = (const float*)d_in[9];
    const float* gamma = (const float*)d_in[10];
    float* out = (float*)d_out;

    char* ws = (char*)d_ws;
    float* sig = (float*)ws;                      // 3 floats
    u16* wh = (u16*)(ws + 1024);                  // 320x256 bf16 hi, 160 KB
    u16* wl = wh + 320 * 256;                     // lo, 160 KB
    u16* Kc = (u16*)(ws + (1 << 20));             // [b][n][64] hi|lo, 2 MB
    u16* Qc = (u16*)(ws + 3 * (1 << 20));         // 2 MB
    u16* Vb = (u16*)(ws + 5 * (1 << 20));         // [b][c][m], 8 MB

    k_sigma<<<dim3(3), dim3(1024), 0, stream>>>(fw, fu, gw, gu, hww, hu, sig, wh, wl);
    k_proj<<<dim3(64, 4), dim3(512), 0, stream>>>(x, wh, wl, fb, gb, hb, sig,
                                                  Kc, Qc, Vb);
    k_attn<<<dim3(256), dim3(512), 0, stream>>>(x, gamma, Kc, Qc, Vb, out);
}

// Round 6
// 253.599 us; speedup vs baseline: 2.9575x; 1.0696x over previous
//
#include <hip/hip_runtime.h>

// ---------------------------------------------------------------------------
// SAGAN self-attention block, MI355X / gfx950.
// B=4, C=256, H=W=64 (HW=4096), Ck=32.
// v6: split-K flash attention (2 independent blocks/CU, bf16 partials +
// merge kernel); k_proj A-operands pre-packed in MFMA fragment order.
// ---------------------------------------------------------------------------

constexpr int kC   = 256;
constexpr int kHW  = 4096;
constexpr int kB   = 4;
constexpr int kCHW = kC * kHW;

typedef short bf16x8 __attribute__((ext_vector_type(8)));
typedef float f32x4  __attribute__((ext_vector_type(4)));
typedef unsigned short u16;

__device__ __forceinline__ u16 f2bf(float f) {
    union { float f; unsigned u; } v; v.f = f;
    unsigned u = v.u;
    return (u16)((u + 0x7fffu + ((u >> 16) & 1u)) >> 16);  // RNE
}
__device__ __forceinline__ float bf2f(u16 h) {
    union { unsigned u; float f; } v; v.u = ((unsigned)h) << 16;
    return v.f;
}

// ---------------------------------------------------------------------------
// Kernel 1: inverse spectral norms + W -> bf16 hi/lo in MFMA-A-fragment-
// packed order: idx = R*4096 + s*512 + l15*32 + k  (R = co>>4, l15 = co&15,
// s = ci>>5, k = ci&31).  Rows: [0,32)=fw, [32,64)=gw, [64,320)=hww.
// ---------------------------------------------------------------------------
__global__ __launch_bounds__(1024) void k_sigma(
    const float* __restrict__ fw, const float* __restrict__ fu,
    const float* __restrict__ gw, const float* __restrict__ gu,
    const float* __restrict__ hww, const float* __restrict__ hu,
    float* __restrict__ sig, u16* __restrict__ wh, u16* __restrict__ wl)
{
    const int which = blockIdx.x;
    const float* W = which == 0 ? fw : (which == 1 ? gw : hww);
    const float* U = which == 0 ? fu : (which == 1 ? gu : hu);
    const int O = (which == 2) ? 256 : 32;
    const int t = threadIdx.x;

    __shared__ float par[4][256];
    __shared__ float red[256];
    __shared__ __align__(16) float Vv[256];

    {
        const int i = t & 255, och = t >> 8;
        int olim = O - och * 64; olim = olim < 0 ? 0 : (olim > 64 ? 64 : olim);
        float p = 0.f;
        for (int oo = 0; oo < olim; ++oo) {
            const int o = och * 64 + oo;
            p += U[o] * W[o * 256 + i];
        }
        par[och][i] = p;
    }
    __syncthreads();
    float t1 = 0.f;
    if (t < 256) {
        t1 = par[0][t] + par[1][t] + par[2][t] + par[3][t];
        red[t] = t1 * t1;
    }
    __syncthreads();
    for (int s = 128; s > 0; s >>= 1) { if (t < s) red[t] += red[t + s]; __syncthreads(); }
    if (t < 256) Vv[t] = t1 / fmaxf(sqrtf(red[0]), 1e-12f);
    __syncthreads();

    {
        const int o = t & 255, ich = t >> 8;
        float q = 0.f;
        if (o < O) {
            const float4* Wr = (const float4*)(W + (size_t)o * 256 + ich * 64);
            const float4* Vr = (const float4*)(&Vv[ich * 64]);
#pragma unroll
            for (int j = 0; j < 16; ++j) {
                const float4 w = Wr[j]; const float4 v = Vr[j];
                q += w.x * v.x + w.y * v.y + w.z * v.z + w.w * v.w;
            }
        }
        par[ich][o] = q;
    }
    __syncthreads();
    if (t < 256) {
        const float t2 = par[0][t] + par[1][t] + par[2][t] + par[3][t];
        red[t] = t2 * t2;
    }
    __syncthreads();
    for (int s = 128; s > 0; s >>= 1) { if (t < s) red[t] += red[t + s]; __syncthreads(); }
    if (t == 0) {
        const float s2 = red[0];
        sig[which] = fmaxf(sqrtf(s2), 1e-12f) / s2;   // 1/sigma
    }

    // ---- W -> bf16 hi/lo, A-fragment-packed ----
    const int nElem = O * 256;
    const int gbase = (which == 0) ? 0 : (which == 1 ? 32 : 64);  // row base
    for (int i = t; i < nElem; i += 1024) {
        const int o = i >> 8, ci = i & 255;
        const int g = gbase + o;
        const int idx = ((g >> 4) * 8 + (ci >> 5)) * 512 + (g & 15) * 32 + (ci & 31);
        const float f = W[i];
        const u16 h = f2bf(f);
        wh[idx] = h;
        wl[idx] = f2bf(f - bf2f(h));
    }
}

// ---------------------------------------------------------------------------
// Kernel 2: all projections as one MFMA GEMM.  grid (64 n-tiles, 4 b),
// 512 thr (8 waves).  Wave = (nch = wave&3, cohalf = wave>>2).
// A-operands (weights) loaded from fragment-packed global: 1 KB/instr,
// fully coalesced.  x staged fp32 via global_load_lds, column-gathered
// into hi/lo B-frags.  3 MFMAs per K-chunk (wl*xl dropped).
// ---------------------------------------------------------------------------
__global__ __launch_bounds__(512) void k_proj(
    const float* __restrict__ x,
    const u16* __restrict__ wh, const u16* __restrict__ wl,
    const float* __restrict__ fb, const float* __restrict__ gb,
    const float* __restrict__ hb, const float* __restrict__ sig,
    u16* __restrict__ Kc, u16* __restrict__ Qc, u16* __restrict__ Vb)
{
    __shared__ __align__(16) float xs[256][64];  // 64 KB
    __shared__ float bLDS[320];

    const int t = threadIdx.x;
    const int wave = t >> 6, lane = t & 63;
    const int quad = lane >> 4, l15 = lane & 15;
    const int b = blockIdx.y;
    const int n0 = blockIdx.x * 64;
    const int nch = wave & 3, cohalf = wave >> 2;

    // stage x tile [256 ci][64 n]
    {
        const int r4i = lane >> 4, c16 = lane & 15;
        const float* xg = x + (size_t)b * kCHW + (size_t)r4i * kHW + n0 + c16 * 4;
#pragma unroll
        for (int j = 0; j < 8; ++j) {
            const int cibase = (wave * 8 + j) * 4;
            __builtin_amdgcn_global_load_lds(
                (const __attribute__((address_space(1))) void*)(xg + (size_t)cibase * kHW),
                (__attribute__((address_space(3))) void*)&xs[cibase][0], 16, 0, 0);
        }
    }
    if (t < 320) bLDS[t] = (t < 32) ? fb[t] : (t < 64) ? gb[t - 32] : hb[t - 64];
    __syncthreads();

    // B-frags (x) hi/lo for 8 ci-slices; lane = col n
    const int n = nch * 16 + l15;
    bf16x8 bh[8], bl[8];
#pragma unroll
    for (int s = 0; s < 8; ++s) {
        union { u16 a[8]; bf16x8 v; } H, L;
#pragma unroll
        for (int j = 0; j < 8; ++j) {
            const float v = xs[s * 32 + quad * 8 + j][n];
            const u16 h = f2bf(v);
            H.a[j] = h; L.a[j] = f2bf(v - bf2f(h));
        }
        bh[s] = H.v; bl[s] = L.v;
    }

    // A-frag lane base into packed layout
    const u16* whp = wh + l15 * 32 + quad * 8;
    const u16* wlp = wl + l15 * 32 + quad * 8;

    f32x4 acc[10] = {};
#pragma unroll
    for (int c = 0; c < 10; ++c) {
        const size_t base = (size_t)(cohalf * 10 + c) * 4096;
#pragma unroll
        for (int s = 0; s < 8; ++s) {
            const bf16x8 ah = *(const bf16x8*)(whp + base + s * 512);
            const bf16x8 al = *(const bf16x8*)(wlp + base + s * 512);
            acc[c] = __builtin_amdgcn_mfma_f32_16x16x32_bf16(ah, bh[s], acc[c], 0, 0, 0);
            acc[c] = __builtin_amdgcn_mfma_f32_16x16x32_bf16(ah, bl[s], acc[c], 0, 0, 0);
            acc[c] = __builtin_amdgcn_mfma_f32_16x16x32_bf16(al, bh[s], acc[c], 0, 0, 0);
        }
    }

    const float s0 = sig[0], s1 = sig[1], s2 = sig[2];
#pragma unroll
    for (int c = 0; c < 10; ++c) {
        const int cog0 = (cohalf * 10 + c) * 16;
        const float inv = (cog0 < 32) ? s0 : (cog0 < 64) ? s1 : s2;
#pragma unroll
        for (int r = 0; r < 4; ++r) {
            const int co = cog0 + quad * 4 + r;
            const float v = acc[c][r] * inv + bLDS[co];
            if (co < 64) {
                u16* H = (co < 32) ? Kc : Qc;
                const int d = co & 31;
                const u16 h = f2bf(v);
                const u16 l = f2bf(v - bf2f(h));
                const size_t off = (size_t)(b * kHW + n0 + n) * 64;
                H[off + d] = h;
                H[off + 32 + d] = l;
            } else {
                Vb[((size_t)b * kC + (co - 64)) * kHW + n0 + n] = f2bf(v);
            }
        }
    }
}

// ---------------------------------------------------------------------------
// Kernel 3: flash attention v6, split-K.  grid 512 (XCD-swizzled; id>>8 =
// key-half), 512 thr (8 waves) -> 2 independent blocks/CU.  Per block:
// 64 rows x 2048 keys.  Structure identical to v5 inside the loop.
// Epilogue: bf16 partial O + per-row (m,l) to workspace.
// ---------------------------------------------------------------------------
__global__ __launch_bounds__(512, 4) void k_attn(
    const u16* __restrict__ Kc, const u16* __restrict__ Qc,
    const u16* __restrict__ Vb,
    u16* __restrict__ Op, float2* __restrict__ St)
{
    __shared__ __align__(16) u16 Qt[2][4096];   // 16 KB
    __shared__ __align__(16) u16 Pt[4096];      // 8 KB
    __shared__ float2 stLDS[8][16];
    __shared__ float aLDS[64];

    const int t = threadIdx.x;
    const int wave = t >> 6, lane = t & 63;
    const int quad = lane >> 4, l15 = lane & 15;
    const int sg = wave >> 1, half = wave & 1;

    const int id = blockIdx.x;
    const int xcd = id & 7;
    const int b = xcd >> 1;
    const int nb0 = ((xcd & 1) * 32 + ((id >> 3) & 31)) * 64;
    const int mh = id >> 8;                    // key-half
    const int mt0 = mh * 32, mt1 = mt0 + 32;

    const u16* Kb  = Kc + (size_t)b * kHW * 64;
    const u16* Qb  = Qc + (size_t)b * kHW * 64;
    const u16* Vbb = Vb + (size_t)b * kC * kHW;

    const size_t krow = (size_t)(nb0 + sg * 16 + l15) * 64 + (size_t)quad * 8;
    const bf16x8 kh = *(const bf16x8*)(Kb + krow);
    const bf16x8 kl = *(const bf16x8*)(Kb + krow + 32);

    const u16* vrow[2];
#pragma unroll
    for (int ct = 0; ct < 2; ++ct)
        vrow[ct] = Vbb + (size_t)(wave * 32 + ct * 16 + l15) * kHW + quad * 8;

    const int qs_row = lane >> 3, qs_ch = lane & 7;

    f32x4 O[8] = {};
    float mrow = -1e30f, lrow = 0.f;
    bf16x8 vc[4], vn[4];

    // ---- prologue ----
    {
        const int rloc = wave * 8 + qs_row;
        __builtin_amdgcn_global_load_lds(
            (const __attribute__((address_space(1))) void*)
                (Qb + (size_t)(mt0 * 64 + rloc) * 64 + ((qs_ch ^ (rloc & 7)) << 3)),
            (__attribute__((address_space(3))) void*)&Qt[0][wave * 512], 16, 0, 0);
    }
#pragma unroll
    for (int ct = 0; ct < 2; ++ct)
#pragma unroll
        for (int ks = 0; ks < 2; ++ks)
            vc[ct * 2 + ks] = *(const bf16x8*)(vrow[ct] + mt0 * 64 + ks * 32);

    for (int mt = mt0; mt < mt1; ++mt) {
        const int cur = mt & 1;
        const int m0 = mt * 64;

        __syncthreads();   // B1: Qt[cur] ready

        if (mt < mt1 - 1) {
            const int m0n = m0 + 64;
            const int rloc = wave * 8 + qs_row;
            __builtin_amdgcn_global_load_lds(
                (const __attribute__((address_space(1))) void*)
                    (Qb + (size_t)(m0n + rloc) * 64 + ((qs_ch ^ (rloc & 7)) << 3)),
                (__attribute__((address_space(3))) void*)&Qt[cur ^ 1][wave * 512], 16, 0, 0);
        }
        const int m0v = (mt < mt1 - 1) ? m0 + 64 : m0;
#pragma unroll
        for (int ct = 0; ct < 2; ++ct)
#pragma unroll
            for (int ks = 0; ks < 2; ++ks)
                vn[ct * 2 + ks] = *(const bf16x8*)(vrow[ct] + m0v + ks * 32);

        // ---- scores for this wave's m-half ----
        f32x4 s[2];
#pragma unroll
        for (int mi2 = 0; mi2 < 2; ++mi2) {
            const int mi = half * 2 + mi2;
            const int rbase = (mi * 16 + l15) * 64;
            const bf16x8 qhv = *(const bf16x8*)&Qt[cur][rbase + ((quad       ^ (l15 & 7)) << 3)];
            const bf16x8 qlv = *(const bf16x8*)&Qt[cur][rbase + (((quad + 4) ^ (l15 & 7)) << 3)];
            f32x4 a = { 0.f, 0.f, 0.f, 0.f };
            a = __builtin_amdgcn_mfma_f32_16x16x32_bf16(qhv, kl, a, 0, 0, 0);
            a = __builtin_amdgcn_mfma_f32_16x16x32_bf16(qlv, kh, a, 0, 0, 0);
            a = __builtin_amdgcn_mfma_f32_16x16x32_bf16(qhv, kh, a, 0, 0, 0);
            s[mi2] = a;
        }

        // ---- wave-local stats ----
        float lm = s[0][0];
#pragma unroll
        for (int mi2 = 0; mi2 < 2; ++mi2)
#pragma unroll
            for (int r = 0; r < 4; ++r) lm = fmaxf(lm, s[mi2][r]);
        lm = fmaxf(lm, __shfl_xor(lm, 16));
        lm = fmaxf(lm, __shfl_xor(lm, 32));
        float ls = 0.f;
#pragma unroll
        for (int mi2 = 0; mi2 < 2; ++mi2)
#pragma unroll
            for (int r = 0; r < 4; ++r) {
                const float p = __expf(s[mi2][r] - lm);
                s[mi2][r] = p;
                ls += p;
            }
        ls += __shfl_xor(ls, 16);
        ls += __shfl_xor(ls, 32);
        if (lane < 16) stLDS[wave][l15] = make_float2(lm, ls);

        asm volatile("s_waitcnt lgkmcnt(0)\n\ts_barrier" ::: "memory");  // Bstat

        const float2 o2 = stLDS[wave ^ 1][l15];
        const float mnew = fmaxf(mrow, fmaxf(lm, o2.x));
        const float alpha = __expf(mrow - mnew);
        const float bm = __expf(lm - mnew);
        lrow = lrow * alpha + ls * bm + o2.y * __expf(o2.x - mnew);
        mrow = mnew;

        // ---- pack P (scaled by bm), write alpha ----
        {
            const int prow = sg * 16 + l15;
#pragma unroll
            for (int mi2 = 0; mi2 < 2; ++mi2) {
                const float p0 = s[mi2][0] * bm, p1 = s[mi2][1] * bm;
                const float p2 = s[mi2][2] * bm, p3 = s[mi2][3] * bm;
                const unsigned d0 = __builtin_amdgcn_perm(
                    __float_as_uint(p1), __float_as_uint(p0), 0x07060302u);
                const unsigned d1 = __builtin_amdgcn_perm(
                    __float_as_uint(p3), __float_as_uint(p2), 0x07060302u);
                const int mi = half * 2 + mi2;
                const int chunk = 2 * mi + (quad >> 1);
                const int off = prow * 64 + ((chunk ^ (l15 & 7)) << 3) + (quad & 1) * 4;
                *(uint2*)(Pt + off) = make_uint2(d0, d1);
            }
            if (half == 0 && lane < 16) aLDS[sg * 16 + l15] = alpha;
        }

        asm volatile("s_waitcnt lgkmcnt(0)\n\ts_barrier" ::: "memory");  // BP

        // ---- rescale O ----
#pragma unroll
        for (int rg = 0; rg < 4; ++rg) {
            const float4 af = *(const float4*)&aLDS[rg * 16 + quad * 4];
#pragma unroll
            for (int ct = 0; ct < 2; ++ct) {
                O[rg * 2 + ct][0] *= af.x;
                O[rg * 2 + ct][1] *= af.y;
                O[rg * 2 + ct][2] *= af.z;
                O[rg * 2 + ct][3] *= af.w;
            }
        }

        // ---- PV ----
#pragma unroll
        for (int ks = 0; ks < 2; ++ks) {
#pragma unroll
            for (int rg = 0; rg < 4; ++rg) {
                const bf16x8 pa = *(const bf16x8*)&Pt[(rg * 16 + l15) * 64
                                     + (((ks * 4 + quad) ^ (l15 & 7)) << 3)];
#pragma unroll
                for (int ct = 0; ct < 2; ++ct)
                    O[rg * 2 + ct] = __builtin_amdgcn_mfma_f32_16x16x32_bf16(
                        pa, vc[ct * 2 + ks], O[rg * 2 + ct], 0, 0, 0);
            }
        }

#pragma unroll
        for (int i = 0; i < 4; ++i) vc[i] = vn[i];
    }

    // ---- epilogue: bf16 partial O + stats ----
    if (half == 0 && lane < 16)
        St[(size_t)(mh * 4 + b) * kHW + nb0 + sg * 16 + l15] = make_float2(mrow, lrow);

    u16* Opb = Op + (size_t)(mh * 4 + b) * kHW * 256;
#pragma unroll
    for (int rg = 0; rg < 4; ++rg) {
#pragma unroll
        for (int ct = 0; ct < 2; ++ct) {
#pragma unroll
            for (int r = 0; r < 4; ++r) {
                const int nn = nb0 + rg * 16 + quad * 4 + r;
                const int c = wave * 32 + ct * 16 + l15;
                Opb[(size_t)nn * 256 + c] = f2bf(O[rg * 2 + ct][r]);
            }
        }
    }
}

// ---------------------------------------------------------------------------
// Kernel 4: merge the two key-halves + epilogue.  grid 2048 x 256 thr,
// 8 channels per thread, fully coalesced.
// ---------------------------------------------------------------------------
__global__ __launch_bounds__(256) void k_merge(
    const float* __restrict__ x, const float* __restrict__ gamma,
    const u16* __restrict__ Op, const float2* __restrict__ St,
    float* __restrict__ out)
{
    const int tid = blockIdx.x * 256 + threadIdx.x;
    const int cg = tid & 31;
    const int n  = (tid >> 5) & 4095;
    const int b  = tid >> 17;
    const int c0 = cg * 8;

    const float2 sa = St[(size_t)b * kHW + n];
    const float2 sb = St[(size_t)(4 + b) * kHW + n];
    const float M  = fmaxf(sa.x, sb.x);
    const float wa = __expf(sa.x - M), wb = __expf(sb.x - M);
    const float invL = 1.f / (sa.y * wa + sb.y * wb);
    const float fa = wa * invL, fb2 = wb * invL;
    const float g = gamma[0];

    const size_t base = ((size_t)b * kHW + n) * 256 + c0;
    const uint4 A = *(const uint4*)(Op + base);
    const uint4 B = *(const uint4*)(Op + base + (size_t)4 * kHW * 256);
    const float4 x0 = *(const float4*)(x + base);
    const float4 x1 = *(const float4*)(x + base + 4);

    float o[8];
    const unsigned aw[4] = { A.x, A.y, A.z, A.w };
    const unsigned bw[4] = { B.x, B.y, B.z, B.w };
#pragma unroll
    for (int j = 0; j < 8; ++j) {
        const float va = bf2f((u16)(aw[j >> 1] >> ((j & 1) * 16)));
        const float vb = bf2f((u16)(bw[j >> 1] >> ((j & 1) * 16)));
        o[j] = va * fa + vb * fb2;
    }
    float4 r0, r1;
    r0.x = g * o[0] + x0.x; r0.y = g * o[1] + x0.y;
    r0.z = g * o[2] + x0.z; r0.w = g * o[3] + x0.w;
    r1.x = g * o[4] + x1.x; r1.y = g * o[5] + x1.y;
    r1.z = g * o[6] + x1.z; r1.w = g * o[7] + x1.w;
    *(float4*)(out + base)     = r0;
    *(float4*)(out + base + 4) = r1;
}

// ---------------------------------------------------------------------------
extern "C" void kernel_launch(void* const* d_in, const int* in_sizes, int n_in,
                              void* d_out, int out_size, void* d_ws, size_t ws_size,
                              hipStream_t stream)
{
    const float* x     = (const float*)d_in[0];
    const float* fw    = (const float*)d_in[1];
    const float* fb    = (const float*)d_in[2];
    const float* fu    = (const float*)d_in[3];
    const float* gw    = (const float*)d_in[4];
    const float* gb    = (const float*)d_in[5];
    const float* gu    = (const float*)d_in[6];
    const float* hww   = (const float*)d_in[7];
    const float* hb    = (const float*)d_in[8];
    const float* hu    = (const float*)d_in[9];
    const float* gamma = (const float*)d_in[10];
    float* out = (float*)d_out;

    char* ws = (char*)d_ws;
    float* sig = (float*)ws;                        // 3 floats
    u16* wh = (u16*)(ws + 1024);                    // packed 320x256 bf16 hi
    u16* wl = wh + 320 * 256;                       // packed lo
    u16* Kc = (u16*)(ws + (1u << 20));              // 2 MB
    u16* Qc = (u16*)(ws + (3u << 20));              // 2 MB
    u16* Vb = (u16*)(ws + (5u << 20));              // 8 MB
    u16* Op = (u16*)(ws + (16u << 20));             // 16 MB: [2][4][4096][256] bf16
    float2* St = (float2*)(ws + (32u << 20));       // 256 KB: [2][4][4096]

    k_sigma<<<dim3(3), dim3(1024), 0, stream>>>(fw, fu, gw, gu, hww, hu, sig, wh, wl);
    k_proj<<<dim3(64, 4), dim3(512), 0, stream>>>(x, wh, wl, fb, gb, hb, sig,
                                                  Kc, Qc, Vb);
    k_attn<<<dim3(512), dim3(512), 0, stream>>>(Kc, Qc, Vb, Op, St);
    k_merge<<<dim3(2048), dim3(256), 0, stream>>>(x, gamma, Op, St, out);
}